// Round 4
// baseline (275.603 us; speedup 1.0000x reference)
//
#include <hip/hip_runtime.h>
#include <stdint.h>

#define DEVI __device__ __forceinline__

typedef unsigned short ushort_t;
typedef __bf16 bf16x8 __attribute__((ext_vector_type(8)));
typedef float f32x4 __attribute__((ext_vector_type(4)));
typedef unsigned short ushort8 __attribute__((ext_vector_type(8)));
typedef short s16x4 __attribute__((ext_vector_type(4)));

// ---- constants ----
#define BB 4
#define TT 2048
#define CC 1024
#define NH 16
#define HD 64
#define MM (BB*TT)          // 8192

// native RNE f32->bf16 (compiler pairs into v_cvt_pk_bf16_f32; m240)
DEVI ushort_t f2bf(float f) {
    __bf16 h = (__bf16)f;
    return __builtin_bit_cast(ushort_t, h);
}

typedef const __attribute__((address_space(1))) unsigned int guint_t;
typedef __attribute__((address_space(3))) unsigned int luint_t;

// async global->LDS, 16B/lane; lds dest is wave-uniform base + lane*16
DEVI void gl2lds16(const void* g, void* lds) {
    __builtin_amdgcn_global_load_lds((guint_t*)(uintptr_t)g,
                                     (luint_t*)(unsigned int)(uintptr_t)lds,
                                     16, 0, 0);
}

template <int N> DEVI void waitvm() {
    static_assert(N == 0 || N == 6, "unsupported vmcnt literal");
    if constexpr (N == 0)      asm volatile("s_waitcnt vmcnt(0)" ::: "memory");
    else if constexpr (N == 6) asm volatile("s_waitcnt vmcnt(6)" ::: "memory");
}

#define BARF() do { asm volatile("" ::: "memory"); \
                    __builtin_amdgcn_s_barrier(); \
                    asm volatile("" ::: "memory"); } while (0)
#define LGK0() asm volatile("s_waitcnt lgkmcnt(0)" ::: "memory")

// ---------------- fp32 -> bf16 bulk convert (8 elems/thread) ----------------
__global__ void cvt_f32_bf16(const float* __restrict__ in,
                             ushort_t* __restrict__ out) {
    int i = blockIdx.x * 256 + threadIdx.x;
    const float4* p = (const float4*)in + (size_t)i * 2;
    float4 a = p[0], b = p[1];
    ushort8 r;
    r[0] = f2bf(a.x); r[1] = f2bf(a.y); r[2] = f2bf(a.z); r[3] = f2bf(a.w);
    r[4] = f2bf(b.x); r[5] = f2bf(b.y); r[6] = f2bf(b.z); r[7] = f2bf(b.w);
    *(ushort8*)(out + (size_t)i * 8) = r;
}

// ------------- transpose fp32 -> bf16: in[R][Cc] -> out[Cc][R] -------------
__global__ void transpose_f2b(const float* __restrict__ in,
                              ushort_t* __restrict__ out, int R, int Cc) {
    __shared__ ushort_t tile[32][33];
    int bx = blockIdx.x * 32;
    int by = blockIdx.y * 32;
    int tx = threadIdx.x & 31, ty = threadIdx.x >> 5;
    #pragma unroll
    for (int i = 0; i < 4; i++) {
        int r = ty * 4 + i;
        tile[r][tx] = f2bf(in[(size_t)(by + r) * Cc + bx + tx]);
    }
    __syncthreads();
    #pragma unroll
    for (int i = 0; i < 4; i++) {
        int r = ty * 4 + i;
        out[(size_t)(bx + r) * R + by + tx] = tile[tx][r];
    }
}

// ---------------- rope table: tab[t*32+j] = (cos, sin) ----------------
__global__ void rope_table(float2* __restrict__ tab) {
    int i = blockIdx.x * 256 + threadIdx.x;   // 65536 total
    int t = i >> 5, j = i & 31;
    float inv = exp2f((float)j * -0.41524101186092029f);
    float theta = (float)t * inv;
    float s, c;
    sincosf(theta, &s, &c);
    tab[i] = make_float2(c, s);
}

// ------- V transpose: Vb[bh][t][d] -> VbT[bh][d][t], 64x64 tiles -------
__global__ void vtrans(const ushort_t* __restrict__ Vb,
                       ushort_t* __restrict__ VbT) {
    __shared__ ushort_t tile[64 * 72];
    const int bh = blockIdx.y;
    const int t0 = blockIdx.x * 64;
    const int tid = threadIdx.x;
    const int r = tid >> 2, c = (tid & 3) * 16;
    const size_t base = (size_t)bh * (TT * HD);
    const ushort_t* g = Vb + base + (size_t)(t0 + r) * HD + c;
    *(ushort8*)&tile[r * 72 + c]     = *(const ushort8*)g;
    *(ushort8*)&tile[r * 72 + c + 8] = *(const ushort8*)(g + 8);
    __syncthreads();
    ushort8 a, b;
    #pragma unroll
    for (int j = 0; j < 8; j++) a[j] = tile[(c + j) * 72 + r];
    #pragma unroll
    for (int j = 0; j < 8; j++) b[j] = tile[(c + 8 + j) * 72 + r];
    ushort_t* o = VbT + base + (size_t)r * TT + t0 + c;
    *(ushort8*)o = a;
    *(ushort8*)(o + 8) = b;
}

// ---------------- GEMM: C = A * Bt^T  (A,Bt bf16) --------------------------
// 128x256 tile, BK=64, 512 threads = 8 waves (2M x 4N), wave tile 64x64.
// 4-phase-per-K-tile schedule (T3+T4): each phase = {frag ds_reads, 2 stage
// lines, barrier, lgkmcnt(0), setprio+8 MFMA, barrier}; double-buffered LDS;
// vmcnt(6) ONCE per K-tile (tile t+2's 6 lines stay in flight across the
// buffer swap). T2 XOR-swizzle via pre-swizzled global source (conflicts=0,
// verified r3). T1 XCD-bijective block swizzle. Exact-round grids.
// Phase safety: buf p's A-lines last read ph3, B-lines ph2 (retired by each
// phase's lgkmcnt(0), ordered by its closing barrier) -> t+2 stages into
// buf p at ph4; t+1 stages into buf p^1 at ph1-3 (its readers ended at tile
// t-1's ph4 barrier); ph4's vmcnt(6) retires all of t+1's 6 lines.
// MODE 1: A=[M][Kd] row-major; qkv epilogue: rope q,k (q pre-scaled by
//         scale*log2e); scatter to [B*NH][T][HD]
// MODE 2: A head-major [(b*16+h)*2048+t][64]; fp32 store to CoutF[M][N]
template <int MODE>
__global__ __launch_bounds__(512, 2) void gemm_bt(
    const ushort_t* __restrict__ A, const ushort_t* __restrict__ Bt,
    float* __restrict__ CoutF,
    ushort_t* __restrict__ Qb, ushort_t* __restrict__ Kb, ushort_t* __restrict__ Vb,
    const float2* __restrict__ rope, int M, int N, int Kd) {
    constexpr int NK = CC / 64;      // 16 K-tiles (Kd == 1024 for both GEMMs)
    (void)M;

    __shared__ __attribute__((aligned(16))) ushort_t As[2][128 * 64];
    __shared__ __attribute__((aligned(16))) ushort_t Bs[2][256 * 64];

    const int tid = threadIdx.x;
    const int w = tid >> 6, l = tid & 63;
    const int lane15 = l & 15, quad = l >> 4;
    const int wm = (w >> 2) * 64;            // wave M offset (0 or 64)
    const int wn = (w & 3) * 64;             // wave N offset

    // XCD-aware bijective swizzle (both grids are multiples of 8 blocks)
    const int nbn = gridDim.x;
    const int nwg = nbn * gridDim.y;
    const int lid = blockIdx.y * nbn + blockIdx.x;
    const int sid = (lid & 7) * (nwg >> 3) + (lid >> 3);
    const int bn = sid % nbn, bm = sid / nbn;

    const int sr = tid >> 3;     // staged row within 64-row line
    const int sc = tid & 7;      // 16B slot within 128B row
    const int srcswz = (sc ^ (sr & 7)) * 16;   // involution w/ read-side XOR

    // one staging "line" = 64 rows x 64 cols bf16 = 8KB = one gl2lds16/thread
    auto stA = [&](int buf, int t, int ln) {
        int gr = bm * 128 + ln * 64 + sr;
        size_t e;
        if constexpr (MODE == 2)
            e = (size_t)(gr >> 11) * 2097152 + (size_t)t * 131072
                + (size_t)(gr & (TT - 1)) * 64;
        else
            e = (size_t)gr * (size_t)Kd + (size_t)t * 64;
        gl2lds16((const char*)(A + e) + srcswz,
                 (char*)&As[buf][0] + ln * 8192 + tid * 16);
    };
    auto stB = [&](int buf, int t, int ln) {
        int gr = bn * 256 + ln * 64 + sr;
        size_t e = (size_t)gr * (size_t)Kd + (size_t)t * 64;
        gl2lds16((const char*)(Bt + e) + srcswz,
                 (char*)&Bs[buf][0] + ln * 8192 + tid * 16);
    };

    f32x4 acc[4][4];
    #pragma unroll
    for (int m = 0; m < 4; ++m)
        #pragma unroll
        for (int n = 0; n < 4; ++n)
            acc[m][n] = f32x4{0.f, 0.f, 0.f, 0.f};

    // prologue: tile 0 fully staged, then enter steady state
    stA(0, 0, 0); stA(0, 0, 1);
    stB(0, 0, 0); stB(0, 0, 1); stB(0, 0, 2); stB(0, 0, 3);
    waitvm<0>();
    BARF();

    const int swz = (lane15 & 7) << 4;   // read-side XOR (row&7 == lane15&7)
    bf16x8 aR[2][2];        // current mh: [m-sub][kk]
    bf16x8 bR[2][2][2];     // [nh][n-sub][kk]

#define LDA_SET(P, MH)                                                        \
    { _Pragma("unroll") for (int i = 0; i < 2; ++i)                           \
      _Pragma("unroll") for (int kk = 0; kk < 2; ++kk)                        \
        aR[i][kk] = *(const bf16x8*)((const char*)&As[P][0] +                 \
            (wm + MH * 32 + i * 16 + lane15) * 128 +                          \
            ((kk * 64 + quad * 16) ^ swz)); }

#define LDB_SET(P, NH)                                                        \
    { _Pragma("unroll") for (int j = 0; j < 2; ++j)                           \
      _Pragma("unroll") for (int kk = 0; kk < 2; ++kk)                        \
        bR[NH][j][kk] = *(const bf16x8*)((const char*)&Bs[P][0] +             \
            (wn + (NH * 2 + j) * 16 + lane15) * 128 +                         \
            ((kk * 64 + quad * 16) ^ swz)); }

#define MFMA_Q(MH, NH)                                                        \
    { __builtin_amdgcn_s_setprio(1);                                          \
      _Pragma("unroll") for (int kk = 0; kk < 2; ++kk)                        \
      _Pragma("unroll") for (int i = 0; i < 2; ++i)                           \
      _Pragma("unroll") for (int j = 0; j < 2; ++j)                           \
        acc[MH * 2 + i][NH * 2 + j] =                                         \
            __builtin_amdgcn_mfma_f32_16x16x32_bf16(                          \
                aR[i][kk], bR[NH][j][kk], acc[MH * 2 + i][NH * 2 + j],        \
                0, 0, 0);                                                     \
      __builtin_amdgcn_s_setprio(0); }

    for (int t = 0; t < NK; ++t) {
        const int p = t & 1;
        const bool st1 = (t + 1 < NK);
        // ---- phase 1: quadrant (0,0) ----
        LDA_SET(p, 0);
        LDB_SET(p, 0);
        if (st1) { stA(p ^ 1, t + 1, 0); stA(p ^ 1, t + 1, 1); }
        BARF(); LGK0();
        MFMA_Q(0, 0);
        BARF();
        // ---- phase 2: quadrant (0,1) ----
        LDB_SET(p, 1);
        if (st1) { stB(p ^ 1, t + 1, 0); stB(p ^ 1, t + 1, 1); }
        BARF(); LGK0();
        MFMA_Q(0, 1);
        BARF();
        // ---- phase 3: quadrant (1,1) ----
        LDA_SET(p, 1);
        if (st1) { stB(p ^ 1, t + 1, 2); stB(p ^ 1, t + 1, 3); }
        BARF(); LGK0();
        MFMA_Q(1, 1);
        BARF();
        // ---- phase 4: quadrant (1,0); stage t+2 into just-freed buf p ----
        if (t + 2 < NK) {
            stA(p, t + 2, 0); stA(p, t + 2, 1);
            stB(p, t + 2, 0); stB(p, t + 2, 1);
            stB(p, t + 2, 2); stB(p, t + 2, 3);
        }
        MFMA_Q(1, 0);
        if (st1) {
            if (t + 2 < NK) waitvm<6>();   // t+1 complete; t+2's 6 in flight
            else            waitvm<0>();
            BARF();
        }
    }
#undef LDA_SET
#undef LDB_SET
#undef MFMA_Q

    if constexpr (MODE == 1) {
        const float SCQ = 0.125f * 1.4426950408889634f;   // folded into Q
        const int colbase = bn * 256 + wn;          // multiple of 64
        const int seg = colbase >> 10;              // 0=q 1=k 2=v
        const int h = (colbase & 1023) >> 6;        // head
        #pragma unroll
        for (int m = 0; m < 4; ++m) {
            int row0 = bm * 128 + wm + m * 16 + quad * 4;
            #pragma unroll
            for (int r = 0; r < 4; ++r) {
                int row = row0 + r;
                int b = row >> 11, t = row & (TT - 1);
                size_t ob = ((size_t)(b * NH + h) * TT + t) * HD;
                if (seg == 2) {
                    #pragma unroll
                    for (int n = 0; n < 4; ++n)
                        Vb[ob + n * 16 + lane15] = f2bf(acc[m][n][r]);
                } else {
                    ushort_t* dst = (seg == 0) ? Qb : Kb;
                    #pragma unroll
                    for (int n = 0; n < 2; ++n) {
                        int j = n * 16 + lane15;        // 0..31
                        float2 cs = rope[t * 32 + j];
                        float x1 = acc[m][n][r];        // d = j
                        float x2 = acc[m][n + 2][r];    // d = j+32
                        float y1 = x1 * cs.x - x2 * cs.y;
                        float y2 = x2 * cs.x + x1 * cs.y;
                        if (seg == 0) { y1 *= SCQ; y2 *= SCQ; }
                        dst[ob + j]      = f2bf(y1);
                        dst[ob + 32 + j] = f2bf(y2);
                    }
                }
            }
        }
    } else {
        #pragma unroll
        for (int m = 0; m < 4; ++m) {
            #pragma unroll
            for (int r = 0; r < 4; ++r) {
                size_t rb = (size_t)(bm * 128 + wm + m * 16 + quad * 4 + r) * N
                            + bn * 256 + wn;
                #pragma unroll
                for (int n = 0; n < 4; ++n)
                    CoutF[rb + n * 16 + lane15] = acc[m][n][r];
            }
        }
    }
}

// ---------------- flash attention (causal), O in place over Q --------------
// grid: (16 q-tiles, B*NH) = 1024 blocks, all co-resident (4/CU).
// XCD-clustered remap: XCD d&7 owns heads [xcd*8, xcd*8+8) (K/V L2 reuse,
// proven -4.4x FETCH). qt permuted via nibble table so stride-32 CU-cohorts
// {p[x],p[x+4],p[x+8],p[x+12]} each sum to 30 -> balanced per-CU work.
// S^T = K*Q^T: S^T's C-frag (kcol=quad*4+reg, qrow=lane15) IS the A-operand
// layout of mfma_16x16x16_bf16 -> P never touches LDS. Q pre-scaled by
// scale*log2e in GEMM1, so scores are already in the exp2 domain.
// Shuffle-free steady state: defer-max checked on IN-LANE partial max only
// (exact as a bound test); row-sum l via ones-column MFMA (C-frag domain,
// same layout as o -> epilogue needs no broadcast). Single barrier per
// k-tile via double-buffered K/V LDS.
__global__ __launch_bounds__(512, 4) void attn_kernel(
    ushort_t* __restrict__ Qb, const ushort_t* __restrict__ Kb,
    const ushort_t* __restrict__ VbT) {
    __shared__ __attribute__((aligned(16))) ushort_t Ks[2][64 * 72]; // K [t][d]
    __shared__ __attribute__((aligned(16))) ushort_t Vs[2][64 * 72]; // V^T [d][t]

    const int tid = threadIdx.x;
    const int w = tid >> 6, l = tid & 63;
    const int lane15 = l & 15, quad = l >> 4;

    const int d = blockIdx.y * gridDim.x + blockIdx.x;
    const int xcd = d & 7, j = d >> 3;
    const int bh = xcd * 8 + (j & 7);
    // qt perm: {15,14,13,12, 0,1,2,3, 11,10,9,8, 4,5,6,7} (nibbles, i=0 low)
    const int qt = (int)((0x765489AB3210CDEFull >> (4 * (j >> 3))) & 15);
    const size_t base = (size_t)bh * (TT * HD);

    const int sr = tid >> 3;         // staging row 0..63
    const int sd = (tid & 7) * 8;    // staging col (elems), 16B per thread
    const ushort_t* kgb = Kb  + base + (size_t)sr * HD + sd;   // + kt*64*HD
    const ushort_t* vgb = VbT + base + (size_t)sr * TT + sd;   // + kt*64

    const int q0 = qt * 128;
    const int rbase = q0 + w * 16;     // wave owns 16 q-rows
    const int ktmax = 2 * qt + 1;      // >= 1 always

    // Q fragments (B-operand of S^T: n=lane15->qrow, k=quad*8+j->dim)
    bf16x8 qf0, qf1;
    {
        const ushort_t* qp = Qb + base + (size_t)(rbase + lane15) * HD + quad * 8;
        qf0 = *(const bf16x8*)qp;
        qf1 = *(const bf16x8*)(qp + 32);
    }

    f32x4 o[4];
    #pragma unroll
    for (int nt = 0; nt < 4; nt++) o[nt] = f32x4{0.f, 0.f, 0.f, 0.f};
    f32x4 lacc = f32x4{0.f, 0.f, 0.f, 0.f};   // row-sum, C-frag domain
    float mrow = -INFINITY;                    // per qrow=lane15

    const s16x4 ONES = {(short)0x3F80, (short)0x3F80,
                        (short)0x3F80, (short)0x3F80};   // bf16 1.0 x4

    // prologue: tile 0 -> buf0; tile 1 -> regs
    ushort8 kr = *(const ushort8*)kgb;
    ushort8 vr = *(const ushort8*)vgb;
    *(ushort8*)&Ks[0][sr * 72 + sd] = kr;
    *(ushort8*)&Vs[0][sr * 72 + sd] = vr;
    kr = *(const ushort8*)(kgb + (size_t)64 * HD);
    vr = *(const ushort8*)(vgb + 64);
    __syncthreads();

    for (int kt = 0; kt <= ktmax; kt++) {
        const int buf = kt & 1;
        // at loop top kr/vr hold tile kt+1; write it to the other buffer
        // (its previous readers finished before the end-of-iter barrier)
        if (kt < ktmax) {
            *(ushort8*)&Ks[buf ^ 1][sr * 72 + sd] = kr;
            *(ushort8*)&Vs[buf ^ 1][sr * 72 + sd] = vr;
        }
        if (kt + 2 <= ktmax) {   // prefetch tile kt+2; overlaps compute
            kr = *(const ushort8*)(kgb + (size_t)(kt + 2) * 64 * HD);
            vr = *(const ushort8*)(vgb + (size_t)(kt + 2) * 64);
        }

        // waves 0-3's last tile can be fully causally masked: skip compute
        // (wave-uniform guard; the barrier below stays outside it)
        if (kt * 64 <= rbase + 15) {
            // S^T tiles: D[kcol][qrow], kcol=c*16+quad*4+reg, qrow=lane15
            f32x4 s[4];
            #pragma unroll
            for (int c = 0; c < 4; c++) {
                bf16x8 k0 = *(const bf16x8*)&Ks[buf][(c * 16 + lane15) * 72 + quad * 8];
                bf16x8 k1 = *(const bf16x8*)&Ks[buf][(c * 16 + lane15) * 72 + 32 + quad * 8];
                f32x4 z = f32x4{0.f, 0.f, 0.f, 0.f};
                z = __builtin_amdgcn_mfma_f32_16x16x32_bf16(k0, qf0, z, 0, 0, 0);
                s[c] = __builtin_amdgcn_mfma_f32_16x16x32_bf16(k1, qf1, z, 0, 0, 0);
            }

            const int qrow = rbase + lane15;
            if (kt * 64 + 63 > rbase) {   // masking needed (wave-uniform)
                #pragma unroll
                for (int c = 0; c < 4; c++)
                    #pragma unroll
                    for (int r = 0; r < 4; r++)
                        if (kt * 64 + c * 16 + quad * 4 + r > qrow) s[c][r] = -1e9f;
            }

            // in-lane partial max (v_max3 triples: 8 ops)
            float a0 = fmaxf(fmaxf(s[0][0], s[0][1]), s[0][2]);
            float a1 = fmaxf(fmaxf(s[0][3], s[1][0]), s[1][1]);
            float a2 = fmaxf(fmaxf(s[1][2], s[1][3]), s[2][0]);
            float a3 = fmaxf(fmaxf(s[2][1], s[2][2]), s[2][3]);
            float a4 = fmaxf(fmaxf(s[3][0], s[3][1]), s[3][2]);
            float mt = fmaxf(fmaxf(a0, a1), a2);
            mt = fmaxf(fmaxf(mt, a3), fmaxf(a4, s[3][3]));

            // defer-max: partial <= bound for all lanes  <=>  row max <= bound
            if (!__all(mt - mrow <= 8.0f)) {
                float mf = fmaxf(mt, __shfl_xor(mt, 16, 64));
                mf = fmaxf(mf, __shfl_xor(mf, 32, 64));
                float mn = fmaxf(mrow, mf);
                float alpha = __builtin_amdgcn_exp2f(mrow - mn);
                mrow = mn;
                #pragma unroll
                for (int r = 0; r < 4; r++) {
                    float aO = __shfl(alpha, quad * 4 + r, 64);
                    #pragma unroll
                    for (int nt = 0; nt < 4; nt++) o[nt][r] *= aO;
                    lacc[r] *= aO;
                }
            }

            // P A-frags (m->qrow, k=quad*4+j->kcol) == S^T C-frag; P bounded
            // by 2^8 (defer). l accumulates P via ones-column MFMA.
            #pragma unroll
            for (int c = 0; c < 4; c++) {
                s16x4 pf;
                #pragma unroll
                for (int r = 0; r < 4; r++)
                    pf[r] = (short)f2bf(__builtin_amdgcn_exp2f(s[c][r] - mrow));
                lacc = __builtin_amdgcn_mfma_f32_16x16x16bf16_1k(
                    pf, ONES, lacc, 0, 0, 0);
                #pragma unroll
                for (int nt = 0; nt < 4; nt++) {
                    s16x4 vf = *(const s16x4*)&Vs[buf][(nt * 16 + lane15) * 72 +
                                                      c * 16 + quad * 4];
                    o[nt] = __builtin_amdgcn_mfma_f32_16x16x16bf16_1k(
                        pf, vf, o[nt], 0, 0, 0);
                }
            }
        }

        if (kt < ktmax) __syncthreads();   // release buf^1 writers / buf readers
    }

    // epilogue: O in place over this wave's Q rows (head-major); l is in the
    // same C-frag domain as o -> no broadcast needed
    #pragma unroll
    for (int r = 0; r < 4; r++) {
        float lO = 1.0f / lacc[r];
        size_t rb = base + (size_t)(rbase + quad * 4 + r) * HD;
        #pragma unroll
        for (int nt = 0; nt < 4; nt++)
            Qb[rb + nt * 16 + lane15] = f2bf(o[nt][r] * lO);
    }
}

// ---------------- launch ----------------
extern "C" void kernel_launch(void* const* d_in, const int* in_sizes, int n_in,
                              void* d_out, int out_size, void* d_ws, size_t ws_size,
                              hipStream_t stream) {
    const float* x    = (const float*)d_in[0];   // [8192][1024] fp32
    const float* wqkv = (const float*)d_in[1];   // [1024][3072] fp32
    const float* wout = (const float*)d_in[2];   // [1024][1024] fp32
    float* out = (float*)d_out;                  // [8192][1024] fp32

    // ws layout (72.5 MiB total):
    char* ws = (char*)d_ws;
    ushort_t* WqkvT = (ushort_t*)(ws);                        // [3072][1024] bf16
    ushort_t* WoutT = (ushort_t*)(ws + 6291456);              // [1024][1024] bf16
    float2*   rope  = (float2*)  (ws + 8388608);              // [2048*32]
    ushort_t* Xb    = (ushort_t*)(ws + 8912896);              // [8192][1024] bf16
    ushort_t* Qb    = (ushort_t*)(ws + 8912896 + 16777216);   // [64][2048][64]
    ushort_t* Kb    = (ushort_t*)(ws + 8912896 + 2 * 16777216);
    ushort_t* Vb    = (ushort_t*)(ws + 8912896 + 3 * 16777216);
    // VbT aliases Xb: Xb is dead after GEMM1, VbT produced after GEMM1.
    ushort_t* VbT   = Xb;                                     // [64][64][2048]

    cvt_f32_bf16<<<dim3(MM * CC / (256 * 8)), 256, 0, stream>>>(x, Xb);
    transpose_f2b<<<dim3(3 * CC / 32, CC / 32), 256, 0, stream>>>(wqkv, WqkvT, CC, 3 * CC);
    transpose_f2b<<<dim3(CC / 32, CC / 32), 256, 0, stream>>>(wout, WoutT, CC, CC);
    rope_table<<<dim3(256), 256, 0, stream>>>(rope);

    // 128x256 tiles: grid1 = 12x64 = 768 blocks (3 exact CU-rounds),
    // grid2 = 4x64 = 256 blocks (1 exact round); both %8==0 for XCD swizzle.
    gemm_bt<1><<<dim3(3 * CC / 256, MM / 128), 512, 0, stream>>>(
        Xb, WqkvT, nullptr, Qb, Kb, Vb, rope, MM, 3 * CC, CC);

    vtrans<<<dim3(TT / 64, BB * NH), 256, 0, stream>>>(Vb, VbT);

    attn_kernel<<<dim3(16, BB * NH), 512, 0, stream>>>(Qb, Kb, VbT);

    gemm_bt<2><<<dim3(CC / 256, MM / 128), 512, 0, stream>>>(
        Qb, WoutT, out, nullptr, nullptr, nullptr, nullptr, MM, CC, CC);
}

// Round 5
// 269.735 us; speedup vs baseline: 1.0218x; 1.0218x over previous
//
#include <hip/hip_runtime.h>
#include <stdint.h>

#define DEVI __device__ __forceinline__

typedef unsigned short ushort_t;
typedef __bf16 bf16x8 __attribute__((ext_vector_type(8)));
typedef float f32x4 __attribute__((ext_vector_type(4)));
typedef unsigned short ushort8 __attribute__((ext_vector_type(8)));
typedef short s16x4 __attribute__((ext_vector_type(4)));

// ---- constants ----
#define BB 4
#define TT 2048
#define CC 1024
#define NH 16
#define HD 64
#define MM (BB*TT)          // 8192

// native RNE f32->bf16 (compiler pairs into v_cvt_pk_bf16_f32; m240)
DEVI ushort_t f2bf(float f) {
    __bf16 h = (__bf16)f;
    return __builtin_bit_cast(ushort_t, h);
}

typedef const __attribute__((address_space(1))) unsigned int guint_t;
typedef __attribute__((address_space(3))) unsigned int luint_t;

// async global->LDS, 16B/lane; lds dest is wave-uniform base + lane*16
DEVI void gl2lds16(const void* g, void* lds) {
    __builtin_amdgcn_global_load_lds((guint_t*)(uintptr_t)g,
                                     (luint_t*)(unsigned int)(uintptr_t)lds,
                                     16, 0, 0);
}

template <int N> DEVI void waitvm() {
    static_assert(N == 0 || N == 4, "unsupported vmcnt literal");
    if constexpr (N == 0)      asm volatile("s_waitcnt vmcnt(0)" ::: "memory");
    else if constexpr (N == 4) asm volatile("s_waitcnt vmcnt(4)" ::: "memory");
}

#define BARF() do { asm volatile("" ::: "memory"); \
                    __builtin_amdgcn_s_barrier(); \
                    asm volatile("" ::: "memory"); } while (0)
#define LGK0() asm volatile("s_waitcnt lgkmcnt(0)" ::: "memory")

// ---------------- fp32 -> bf16 bulk convert (8 elems/thread) ----------------
__global__ void cvt_f32_bf16(const float* __restrict__ in,
                             ushort_t* __restrict__ out) {
    int i = blockIdx.x * 256 + threadIdx.x;
    const float4* p = (const float4*)in + (size_t)i * 2;
    float4 a = p[0], b = p[1];
    ushort8 r;
    r[0] = f2bf(a.x); r[1] = f2bf(a.y); r[2] = f2bf(a.z); r[3] = f2bf(a.w);
    r[4] = f2bf(b.x); r[5] = f2bf(b.y); r[6] = f2bf(b.z); r[7] = f2bf(b.w);
    *(ushort8*)(out + (size_t)i * 8) = r;
}

// ------------- transpose fp32 -> bf16: in[R][Cc] -> out[Cc][R] -------------
__global__ void transpose_f2b(const float* __restrict__ in,
                              ushort_t* __restrict__ out, int R, int Cc) {
    __shared__ ushort_t tile[32][33];
    int bx = blockIdx.x * 32;
    int by = blockIdx.y * 32;
    int tx = threadIdx.x & 31, ty = threadIdx.x >> 5;
    #pragma unroll
    for (int i = 0; i < 4; i++) {
        int r = ty * 4 + i;
        tile[r][tx] = f2bf(in[(size_t)(by + r) * Cc + bx + tx]);
    }
    __syncthreads();
    #pragma unroll
    for (int i = 0; i < 4; i++) {
        int r = ty * 4 + i;
        out[(size_t)(bx + r) * R + by + tx] = tile[tx][r];
    }
}

// ---------------- rope table: tab[t*32+j] = (cos, sin) ----------------
__global__ void rope_table(float2* __restrict__ tab) {
    int i = blockIdx.x * 256 + threadIdx.x;   // 65536 total
    int t = i >> 5, j = i & 31;
    float inv = exp2f((float)j * -0.41524101186092029f);
    float theta = (float)t * inv;
    float s, c;
    sincosf(theta, &s, &c);
    tab[i] = make_float2(c, s);
}

// ------- V transpose: Vb[bh][t][d] -> VbT[bh][d][t], 64x64 tiles -------
__global__ void vtrans(const ushort_t* __restrict__ Vb,
                       ushort_t* __restrict__ VbT) {
    __shared__ ushort_t tile[64 * 72];
    const int bh = blockIdx.y;
    const int t0 = blockIdx.x * 64;
    const int tid = threadIdx.x;
    const int r = tid >> 2, c = (tid & 3) * 16;
    const size_t base = (size_t)bh * (TT * HD);
    const ushort_t* g = Vb + base + (size_t)(t0 + r) * HD + c;
    *(ushort8*)&tile[r * 72 + c]     = *(const ushort8*)g;
    *(ushort8*)&tile[r * 72 + c + 8] = *(const ushort8*)(g + 8);
    __syncthreads();
    ushort8 a, b;
    #pragma unroll
    for (int j = 0; j < 8; j++) a[j] = tile[(c + j) * 72 + r];
    #pragma unroll
    for (int j = 0; j < 8; j++) b[j] = tile[(c + 8 + j) * 72 + r];
    ushort_t* o = VbT + base + (size_t)r * TT + t0 + c;
    *(ushort8*)o = a;
    *(ushort8*)(o + 8) = b;
}

// ---------------- GEMM: C = A * Bt^T  (A,Bt bf16) --------------------------
// m201 geometry: 256x256 tile, BK=64, 512 threads = 8 waves (2M x 4N),
// per-wave output 128x64 (acc[8][4]), LDS 128 KiB double-buffered.
// 4 phases per K-tile, each = {ds_read subtile + stage 1 half-tile (2
// gl2lds) -> barrier -> lgkmcnt(0) -> setprio + 16 MFMA -> barrier}.
// Snake quadrant order (m0n0, m0n1, m1n1, m1n0): ph4 reuses regs, 0 reads.
// Counted vmcnt(4) once per K-tile: B(t+2)'s 4 loads stay in flight across
// the swap; vmcnt retires all of tile t+1 (FIFO: its 8 loads are older).
// Stage schedule (derived vs reader retirement): A(t+1)->buf p^1 at ph1/ph2
// (that buf idle since t-1); B(t+2)->buf p at ph3/ph4 (Bs[p] reads retire
// at ph2's lgk0+barrier; As[p] reads in ph3 touch As only).
// T2 XOR-swizzle via pre-swizzled global source (conflicts=0, verified r3).
// T1 XCD-bijective block swizzle. T5 setprio.
// MODE 1: A=[M][Kd] row-major; qkv epilogue: rope q,k (q pre-scaled by
//         scale*log2e); scatter to [B*NH][T][HD]
// MODE 2: A head-major [(b*16+h)*2048+t][64]; fp32 store to CoutF[M][N]
template <int MODE>
__global__ __launch_bounds__(512, 2) void gemm_bt(
    const ushort_t* __restrict__ A, const ushort_t* __restrict__ Bt,
    float* __restrict__ CoutF,
    ushort_t* __restrict__ Qb, ushort_t* __restrict__ Kb, ushort_t* __restrict__ Vb,
    const float2* __restrict__ rope, int M, int N, int Kd) {
    constexpr int NK = CC / 64;      // 16 K-tiles (Kd == 1024 for both GEMMs)
    (void)M;

    __shared__ __attribute__((aligned(16))) ushort_t As[2][256 * 64];  // 64 KiB
    __shared__ __attribute__((aligned(16))) ushort_t Bs[2][256 * 64];  // 64 KiB

    const int tid = threadIdx.x;
    const int w = tid >> 6, l = tid & 63;
    const int lane15 = l & 15, quad = l >> 4;
    const int wm = (w >> 2) * 128;           // wave M offset (0 or 128)
    const int wn = (w & 3) * 64;             // wave N offset

    // XCD-aware bijective swizzle (both grids are multiples of 8 blocks)
    const int nbn = gridDim.x;
    const int nwg = nbn * gridDim.y;
    const int lid = blockIdx.y * nbn + blockIdx.x;
    const int sid = (lid & 7) * (nwg >> 3) + (lid >> 3);
    const int bn = sid % nbn, bm = sid / nbn;

    const int sr = tid >> 3;     // staged row within 64-row line
    const int sc = tid & 7;      // 16B slot within 128B row
    const int srcswz = (sc ^ (sr & 7)) * 16;   // involution w/ read-side XOR

    // one staging "line" = 64 rows x 64 cols bf16 = 8KB = one gl2lds16/thread
    auto stA = [&](int buf, int t, int ln) {
        int gr = bm * 256 + ln * 64 + sr;
        size_t e;
        if constexpr (MODE == 2)
            e = (size_t)(gr >> 11) * 2097152 + (size_t)t * 131072
                + (size_t)(gr & (TT - 1)) * 64;
        else
            e = (size_t)gr * (size_t)Kd + (size_t)t * 64;
        gl2lds16((const char*)(A + e) + srcswz,
                 (char*)&As[buf][0] + ln * 8192 + tid * 16);
    };
    auto stB = [&](int buf, int t, int ln) {
        int gr = bn * 256 + ln * 64 + sr;
        size_t e = (size_t)gr * (size_t)Kd + (size_t)t * 64;
        gl2lds16((const char*)(Bt + e) + srcswz,
                 (char*)&Bs[buf][0] + ln * 8192 + tid * 16);
    };

    f32x4 acc[8][4];
    #pragma unroll
    for (int m = 0; m < 8; ++m)
        #pragma unroll
        for (int n = 0; n < 4; ++n)
            acc[m][n] = f32x4{0.f, 0.f, 0.f, 0.f};

    // prologue: tile 0 (A+B, 8 loads) + tile 1's B (4 loads); wait tile 0
    stA(0, 0, 0); stA(0, 0, 1); stA(0, 0, 2); stA(0, 0, 3);
    stB(0, 0, 0); stB(0, 0, 1); stB(0, 0, 2); stB(0, 0, 3);
    stB(1, 1, 0); stB(1, 1, 1); stB(1, 1, 2); stB(1, 1, 3);
    waitvm<4>();
    BARF();

    const int swz = (lane15 & 7) << 4;   // read-side XOR (row&7 == lane15&7)
    bf16x8 aR[4][2];        // current m-half: [m-sub][kk]
    bf16x8 bR[4][2];        // all 4 n-frags:  [n][kk]

#define LDA_H(P, MH)                                                          \
    { _Pragma("unroll") for (int i = 0; i < 4; ++i)                           \
      _Pragma("unroll") for (int kk = 0; kk < 2; ++kk)                        \
        aR[i][kk] = *(const bf16x8*)((const char*)&As[P][0] +                 \
            (wm + MH * 64 + i * 16 + lane15) * 128 +                          \
            ((kk * 64 + quad * 16) ^ swz)); }

#define LDB_H(P, NHF)                                                         \
    { _Pragma("unroll") for (int j = 0; j < 2; ++j)                           \
      _Pragma("unroll") for (int kk = 0; kk < 2; ++kk)                        \
        bR[NHF * 2 + j][kk] = *(const bf16x8*)((const char*)&Bs[P][0] +       \
            (wn + (NHF * 2 + j) * 16 + lane15) * 128 +                        \
            ((kk * 64 + quad * 16) ^ swz)); }

#define MFMA_Q(MH, NHF)                                                       \
    { __builtin_amdgcn_s_setprio(1);                                          \
      _Pragma("unroll") for (int kk = 0; kk < 2; ++kk)                        \
      _Pragma("unroll") for (int i = 0; i < 4; ++i)                           \
      _Pragma("unroll") for (int j = 0; j < 2; ++j)                           \
        acc[MH * 4 + i][NHF * 2 + j] =                                        \
            __builtin_amdgcn_mfma_f32_16x16x32_bf16(                          \
                aR[i][kk], bR[NHF * 2 + j][kk], acc[MH * 4 + i][NHF * 2 + j], \
                0, 0, 0);                                                     \
      __builtin_amdgcn_s_setprio(0); }

    for (int t = 0; t < NK; ++t) {
        const int p = t & 1;
        const bool s1 = (t + 1 < NK), s2 = (t + 2 < NK);
        // ---- ph1: quadrant (m0, n0) + stage A(t+1) h0 -> buf p^1 ----
        LDA_H(p, 0);
        LDB_H(p, 0);
        if (s1) { stA(p ^ 1, t + 1, 0); stA(p ^ 1, t + 1, 1); }
        BARF(); LGK0();
        MFMA_Q(0, 0);
        BARF();
        // ---- ph2: quadrant (m0, n1) + stage A(t+1) h1 ----
        LDB_H(p, 1);
        if (s1) { stA(p ^ 1, t + 1, 2); stA(p ^ 1, t + 1, 3); }
        BARF(); LGK0();
        MFMA_Q(0, 1);
        BARF();
        // ---- ph3: quadrant (m1, n1) + stage B(t+2) h0 -> buf p ----
        LDA_H(p, 1);
        if (s2) { stB(p, t + 2, 0); stB(p, t + 2, 1); }
        BARF(); LGK0();
        MFMA_Q(1, 1);
        BARF();
        // ---- ph4: quadrant (m1, n0), no ds-reads; stage B(t+2) h1 ----
        if (s2) { stB(p, t + 2, 2); stB(p, t + 2, 3); }
        MFMA_Q(1, 0);
        if (s1) {
            if (s2) waitvm<4>();   // tile t+1 landed; B(t+2) in flight
            else    waitvm<0>();
            BARF();
        }
    }
#undef LDA_H
#undef LDB_H
#undef MFMA_Q

    if constexpr (MODE == 1) {
        const float SCQ = 0.125f * 1.4426950408889634f;   // folded into Q
        const int colbase = bn * 256 + wn;          // multiple of 64
        const int seg = colbase >> 10;              // 0=q 1=k 2=v
        const int h = (colbase & 1023) >> 6;        // head
        #pragma unroll
        for (int m = 0; m < 8; ++m) {
            int row0 = bm * 256 + wm + m * 16 + quad * 4;
            #pragma unroll
            for (int r = 0; r < 4; ++r) {
                int row = row0 + r;
                int b = row >> 11, t = row & (TT - 1);
                size_t ob = ((size_t)(b * NH + h) * TT + t) * HD;
                if (seg == 2) {
                    #pragma unroll
                    for (int n = 0; n < 4; ++n)
                        Vb[ob + n * 16 + lane15] = f2bf(acc[m][n][r]);
                } else {
                    ushort_t* dst = (seg == 0) ? Qb : Kb;
                    #pragma unroll
                    for (int n = 0; n < 2; ++n) {
                        int j = n * 16 + lane15;        // 0..31
                        float2 cs = rope[t * 32 + j];
                        float x1 = acc[m][n][r];        // d = j
                        float x2 = acc[m][n + 2][r];    // d = j+32
                        float y1 = x1 * cs.x - x2 * cs.y;
                        float y2 = x2 * cs.x + x1 * cs.y;
                        if (seg == 0) { y1 *= SCQ; y2 *= SCQ; }
                        dst[ob + j]      = f2bf(y1);
                        dst[ob + 32 + j] = f2bf(y2);
                    }
                }
            }
        }
    } else {
        #pragma unroll
        for (int m = 0; m < 8; ++m) {
            #pragma unroll
            for (int r = 0; r < 4; ++r) {
                size_t rb = (size_t)(bm * 256 + wm + m * 16 + quad * 4 + r) * N
                            + bn * 256 + wn;
                #pragma unroll
                for (int n = 0; n < 4; ++n)
                    CoutF[rb + n * 16 + lane15] = acc[m][n][r];
            }
        }
    }
}

// ---------------- flash attention (causal), O in place over Q --------------
// grid: (16 q-tiles, B*NH) = 1024 blocks, all co-resident (4/CU).
// XCD-clustered remap: XCD d&7 owns heads [xcd*8, xcd*8+8) (K/V L2 reuse,
// proven -4.4x FETCH). qt permuted via nibble table so stride-32 CU-cohorts
// {p[x],p[x+4],p[x+8],p[x+12]} each sum to 30 -> balanced per-CU work.
// S^T = K*Q^T: S^T's C-frag (kcol=quad*4+reg, qrow=lane15) IS the A-operand
// layout of mfma_16x16x16_bf16 -> P never touches LDS. Q pre-scaled by
// scale*log2e in GEMM1, so scores are already in the exp2 domain.
// Shuffle-free steady state: defer-max checked on IN-LANE partial max only
// (exact as a bound test); row-sum l via ones-column MFMA (C-frag domain,
// same layout as o -> epilogue needs no broadcast). Single barrier per
// k-tile via double-buffered K/V LDS.
__global__ __launch_bounds__(512, 4) void attn_kernel(
    ushort_t* __restrict__ Qb, const ushort_t* __restrict__ Kb,
    const ushort_t* __restrict__ VbT) {
    __shared__ __attribute__((aligned(16))) ushort_t Ks[2][64 * 72]; // K [t][d]
    __shared__ __attribute__((aligned(16))) ushort_t Vs[2][64 * 72]; // V^T [d][t]

    const int tid = threadIdx.x;
    const int w = tid >> 6, l = tid & 63;
    const int lane15 = l & 15, quad = l >> 4;

    const int d = blockIdx.y * gridDim.x + blockIdx.x;
    const int xcd = d & 7, j = d >> 3;
    const int bh = xcd * 8 + (j & 7);
    // qt perm: {15,14,13,12, 0,1,2,3, 11,10,9,8, 4,5,6,7} (nibbles, i=0 low)
    const int qt = (int)((0x765489AB3210CDEFull >> (4 * (j >> 3))) & 15);
    const size_t base = (size_t)bh * (TT * HD);

    const int sr = tid >> 3;         // staging row 0..63
    const int sd = (tid & 7) * 8;    // staging col (elems), 16B per thread
    const ushort_t* kgb = Kb  + base + (size_t)sr * HD + sd;   // + kt*64*HD
    const ushort_t* vgb = VbT + base + (size_t)sr * TT + sd;   // + kt*64

    const int q0 = qt * 128;
    const int rbase = q0 + w * 16;     // wave owns 16 q-rows
    const int ktmax = 2 * qt + 1;      // >= 1 always

    // Q fragments (B-operand of S^T: n=lane15->qrow, k=quad*8+j->dim)
    bf16x8 qf0, qf1;
    {
        const ushort_t* qp = Qb + base + (size_t)(rbase + lane15) * HD + quad * 8;
        qf0 = *(const bf16x8*)qp;
        qf1 = *(const bf16x8*)(qp + 32);
    }

    f32x4 o[4];
    #pragma unroll
    for (int nt = 0; nt < 4; nt++) o[nt] = f32x4{0.f, 0.f, 0.f, 0.f};
    f32x4 lacc = f32x4{0.f, 0.f, 0.f, 0.f};   // row-sum, C-frag domain
    float mrow = -INFINITY;                    // per qrow=lane15

    const s16x4 ONES = {(short)0x3F80, (short)0x3F80,
                        (short)0x3F80, (short)0x3F80};   // bf16 1.0 x4

    // prologue: tile 0 -> buf0; tile 1 -> regs
    ushort8 kr = *(const ushort8*)kgb;
    ushort8 vr = *(const ushort8*)vgb;
    *(ushort8*)&Ks[0][sr * 72 + sd] = kr;
    *(ushort8*)&Vs[0][sr * 72 + sd] = vr;
    kr = *(const ushort8*)(kgb + (size_t)64 * HD);
    vr = *(const ushort8*)(vgb + 64);
    __syncthreads();

    for (int kt = 0; kt <= ktmax; kt++) {
        const int buf = kt & 1;
        // at loop top kr/vr hold tile kt+1; write it to the other buffer
        // (its previous readers finished before the end-of-iter barrier)
        if (kt < ktmax) {
            *(ushort8*)&Ks[buf ^ 1][sr * 72 + sd] = kr;
            *(ushort8*)&Vs[buf ^ 1][sr * 72 + sd] = vr;
        }
        if (kt + 2 <= ktmax) {   // prefetch tile kt+2; overlaps compute
            kr = *(const ushort8*)(kgb + (size_t)(kt + 2) * 64 * HD);
            vr = *(const ushort8*)(vgb + (size_t)(kt + 2) * 64);
        }

        // waves 0-3's last tile can be fully causally masked: skip compute
        // (wave-uniform guard; the barrier below stays outside it)
        if (kt * 64 <= rbase + 15) {
            // S^T tiles: D[kcol][qrow], kcol=c*16+quad*4+reg, qrow=lane15
            f32x4 s[4];
            #pragma unroll
            for (int c = 0; c < 4; c++) {
                bf16x8 k0 = *(const bf16x8*)&Ks[buf][(c * 16 + lane15) * 72 + quad * 8];
                bf16x8 k1 = *(const bf16x8*)&Ks[buf][(c * 16 + lane15) * 72 + 32 + quad * 8];
                f32x4 z = f32x4{0.f, 0.f, 0.f, 0.f};
                z = __builtin_amdgcn_mfma_f32_16x16x32_bf16(k0, qf0, z, 0, 0, 0);
                s[c] = __builtin_amdgcn_mfma_f32_16x16x32_bf16(k1, qf1, z, 0, 0, 0);
            }

            const int qrow = rbase + lane15;
            if (kt * 64 + 63 > rbase) {   // masking needed (wave-uniform)
                #pragma unroll
                for (int c = 0; c < 4; c++)
                    #pragma unroll
                    for (int r = 0; r < 4; r++)
                        if (kt * 64 + c * 16 + quad * 4 + r > qrow) s[c][r] = -1e9f;
            }

            // in-lane partial max (v_max3 triples: 8 ops)
            float a0 = fmaxf(fmaxf(s[0][0], s[0][1]), s[0][2]);
            float a1 = fmaxf(fmaxf(s[0][3], s[1][0]), s[1][1]);
            float a2 = fmaxf(fmaxf(s[1][2], s[1][3]), s[2][0]);
            float a3 = fmaxf(fmaxf(s[2][1], s[2][2]), s[2][3]);
            float a4 = fmaxf(fmaxf(s[3][0], s[3][1]), s[3][2]);
            float mt = fmaxf(fmaxf(a0, a1), a2);
            mt = fmaxf(fmaxf(mt, a3), fmaxf(a4, s[3][3]));

            // defer-max: partial <= bound for all lanes  <=>  row max <= bound
            if (!__all(mt - mrow <= 8.0f)) {
                float mf = fmaxf(mt, __shfl_xor(mt, 16, 64));
                mf = fmaxf(mf, __shfl_xor(mf, 32, 64));
                float mn = fmaxf(mrow, mf);
                float alpha = __builtin_amdgcn_exp2f(mrow - mn);
                mrow = mn;
                #pragma unroll
                for (int r = 0; r < 4; r++) {
                    float aO = __shfl(alpha, quad * 4 + r, 64);
                    #pragma unroll
                    for (int nt = 0; nt < 4; nt++) o[nt][r] *= aO;
                    lacc[r] *= aO;
                }
            }

            // P A-frags (m->qrow, k=quad*4+j->kcol) == S^T C-frag; P bounded
            // by 2^8 (defer). l accumulates P via ones-column MFMA.
            #pragma unroll
            for (int c = 0; c < 4; c++) {
                s16x4 pf;
                #pragma unroll
                for (int r = 0; r < 4; r++)
                    pf[r] = (short)f2bf(__builtin_amdgcn_exp2f(s[c][r] - mrow));
                lacc = __builtin_amdgcn_mfma_f32_16x16x16bf16_1k(
                    pf, ONES, lacc, 0, 0, 0);
                #pragma unroll
                for (int nt = 0; nt < 4; nt++) {
                    s16x4 vf = *(const s16x4*)&Vs[buf][(nt * 16 + lane15) * 72 +
                                                      c * 16 + quad * 4];
                    o[nt] = __builtin_amdgcn_mfma_f32_16x16x16bf16_1k(
                        pf, vf, o[nt], 0, 0, 0);
                }
            }
        }

        if (kt < ktmax) __syncthreads();   // release buf^1 writers / buf readers
    }

    // epilogue: O in place over this wave's Q rows (head-major); l is in the
    // same C-frag domain as o -> no broadcast needed
    #pragma unroll
    for (int r = 0; r < 4; r++) {
        float lO = 1.0f / lacc[r];
        size_t rb = base + (size_t)(rbase + quad * 4 + r) * HD;
        #pragma unroll
        for (int nt = 0; nt < 4; nt++)
            Qb[rb + nt * 16 + lane15] = f2bf(o[nt][r] * lO);
    }
}

// ---------------- launch ----------------
extern "C" void kernel_launch(void* const* d_in, const int* in_sizes, int n_in,
                              void* d_out, int out_size, void* d_ws, size_t ws_size,
                              hipStream_t stream) {
    const float* x    = (const float*)d_in[0];   // [8192][1024] fp32
    const float* wqkv = (const float*)d_in[1];   // [1024][3072] fp32
    const float* wout = (const float*)d_in[2];   // [1024][1024] fp32
    float* out = (float*)d_out;                  // [8192][1024] fp32

    // ws layout (72.5 MiB total):
    char* ws = (char*)d_ws;
    ushort_t* WqkvT = (ushort_t*)(ws);                        // [3072][1024] bf16
    ushort_t* WoutT = (ushort_t*)(ws + 6291456);              // [1024][1024] bf16
    float2*   rope  = (float2*)  (ws + 8388608);              // [2048*32]
    ushort_t* Xb    = (ushort_t*)(ws + 8912896);              // [8192][1024] bf16
    ushort_t* Qb    = (ushort_t*)(ws + 8912896 + 16777216);   // [64][2048][64]
    ushort_t* Kb    = (ushort_t*)(ws + 8912896 + 2 * 16777216);
    ushort_t* Vb    = (ushort_t*)(ws + 8912896 + 3 * 16777216);
    // VbT aliases Xb: Xb is dead after GEMM1, VbT produced after GEMM1.
    ushort_t* VbT   = Xb;                                     // [64][64][2048]

    cvt_f32_bf16<<<dim3(MM * CC / (256 * 8)), 256, 0, stream>>>(x, Xb);
    transpose_f2b<<<dim3(3 * CC / 32, CC / 32), 256, 0, stream>>>(wqkv, WqkvT, CC, 3 * CC);
    transpose_f2b<<<dim3(CC / 32, CC / 32), 256, 0, stream>>>(wout, WoutT, CC, CC);
    rope_table<<<dim3(256), 256, 0, stream>>>(rope);

    // 256x256 tiles (m201 geometry): grid1 = 12x32 = 384 blocks,
    // grid2 = 4x32 = 128 blocks; both %8==0 for XCD swizzle.
    gemm_bt<1><<<dim3(3 * CC / 256, MM / 256), 512, 0, stream>>>(
        Xb, WqkvT, nullptr, Qb, Kb, Vb, rope, MM, 3 * CC, CC);

    vtrans<<<dim3(TT / 64, BB * NH), 256, 0, stream>>>(Vb, VbT);

    attn_kernel<<<dim3(16, BB * NH), 512, 0, stream>>>(Qb, Kb, VbT);

    gemm_bt<2><<<dim3(CC / 256, MM / 256), 512, 0, stream>>>(
        Qb, WoutT, out, nullptr, nullptr, nullptr, nullptr, MM, CC, CC);
}

// Round 8
// 253.942 us; speedup vs baseline: 1.0853x; 1.0622x over previous
//
#include <hip/hip_runtime.h>
#include <stdint.h>

#define DEVI __device__ __forceinline__

typedef unsigned short ushort_t;
typedef __bf16 bf16x8 __attribute__((ext_vector_type(8)));
typedef float f32x4 __attribute__((ext_vector_type(4)));
typedef unsigned short ushort8 __attribute__((ext_vector_type(8)));
typedef unsigned short u16x4 __attribute__((ext_vector_type(4)));
typedef short s16x4 __attribute__((ext_vector_type(4)));

// ---- constants ----
#define BB 4
#define TT 2048
#define CC 1024
#define NH 16
#define HD 64
#define MM (BB*TT)          // 8192

// native RNE f32->bf16 (compiler pairs into v_cvt_pk_bf16_f32; m240)
DEVI ushort_t f2bf(float f) {
    __bf16 h = (__bf16)f;
    return __builtin_bit_cast(ushort_t, h);
}

typedef const __attribute__((address_space(1))) unsigned int guint_t;
typedef __attribute__((address_space(3))) unsigned int luint_t;

// async global->LDS, 16B/lane; lds dest is wave-uniform base + lane*16
DEVI void gl2lds16(const void* g, void* lds) {
    __builtin_amdgcn_global_load_lds((guint_t*)(uintptr_t)g,
                                     (luint_t*)(unsigned int)(uintptr_t)lds,
                                     16, 0, 0);
}

template <int N> DEVI void waitvm() {
    static_assert(N == 0 || N == 4, "unsupported vmcnt literal");
    if constexpr (N == 0)      asm volatile("s_waitcnt vmcnt(0)" ::: "memory");
    else if constexpr (N == 4) asm volatile("s_waitcnt vmcnt(4)" ::: "memory");
}

#define BARF() do { asm volatile("" ::: "memory"); \
                    __builtin_amdgcn_s_barrier(); \
                    asm volatile("" ::: "memory"); } while (0)
#define LGK0() asm volatile("s_waitcnt lgkmcnt(0)" ::: "memory")

// ---------------- fp32 -> bf16 bulk convert (8 elems/thread) ----------------
__global__ void cvt_f32_bf16(const float* __restrict__ in,
                             ushort_t* __restrict__ out) {
    int i = blockIdx.x * 256 + threadIdx.x;
    const float4* p = (const float4*)in + (size_t)i * 2;
    float4 a = p[0], b = p[1];
    ushort8 r;
    r[0] = f2bf(a.x); r[1] = f2bf(a.y); r[2] = f2bf(a.z); r[3] = f2bf(a.w);
    r[4] = f2bf(b.x); r[5] = f2bf(b.y); r[6] = f2bf(b.z); r[7] = f2bf(b.w);
    *(ushort8*)(out + (size_t)i * 8) = r;
}

// ------------- transpose fp32 -> bf16: in[R][Cc] -> out[Cc][R] -------------
__global__ void transpose_f2b(const float* __restrict__ in,
                              ushort_t* __restrict__ out, int R, int Cc) {
    __shared__ ushort_t tile[32][33];
    int bx = blockIdx.x * 32;
    int by = blockIdx.y * 32;
    int tx = threadIdx.x & 31, ty = threadIdx.x >> 5;
    #pragma unroll
    for (int i = 0; i < 4; i++) {
        int r = ty * 4 + i;
        tile[r][tx] = f2bf(in[(size_t)(by + r) * Cc + bx + tx]);
    }
    __syncthreads();
    #pragma unroll
    for (int i = 0; i < 4; i++) {
        int r = ty * 4 + i;
        out[(size_t)(bx + r) * R + by + tx] = tile[tx][r];
    }
}

// ---------------- rope table: tab[t*32+j] = (cos, sin) ----------------
__global__ void rope_table(float2* __restrict__ tab) {
    int i = blockIdx.x * 256 + threadIdx.x;   // 65536 total
    int t = i >> 5, j = i & 31;
    float inv = exp2f((float)j * -0.41524101186092029f);
    float theta = (float)t * inv;
    float s, c;
    sincosf(theta, &s, &c);
    tab[i] = make_float2(c, s);
}

// ---------------- GEMM: C = A * Bt^T  (A,Bt bf16) --------------------------
// 256x256 tile, BK=64, 512 threads = 8 waves (2M x 4N), per-wave output
// 128x64 (acc[8][4]), LDS 128 KiB double-buffered, 4 phases/K-tile with
// counted vmcnt(4) (unchanged from r5 — best GEMM so far).
// MODE 1: A=[M][Kd] row-major; epilogue: rope q,k (q pre-scaled by
//         scale*log2e) scatter to [B*NH][T][HD]; V written DIRECTLY
//         TRANSPOSED to VbT[bh][d][t] via per-wave LDS round-trip (As/Bs
//         dead post-loop) -> vtrans kernel eliminated.
//         (r7 bug: used GLOBAL row t0 in the VbT store; batch offset was
//         double-counted via obase. Fixed: t local = t0 & (TT-1).)
// MODE 2: A head-major [(b*16+h)*2048+t][64]; fp32 store to CoutF[M][N]
template <int MODE>
__global__ __launch_bounds__(512, 2) void gemm_bt(
    const ushort_t* __restrict__ A, const ushort_t* __restrict__ Bt,
    float* __restrict__ CoutF,
    ushort_t* __restrict__ Qb, ushort_t* __restrict__ Kb, ushort_t* __restrict__ VbT,
    const float2* __restrict__ rope, int M, int N, int Kd) {
    constexpr int NK = CC / 64;      // 16 K-tiles (Kd == 1024 for both GEMMs)
    (void)M;

    __shared__ __attribute__((aligned(16))) ushort_t As[2][256 * 64];  // 64 KiB
    __shared__ __attribute__((aligned(16))) ushort_t Bs[2][256 * 64];  // 64 KiB

    const int tid = threadIdx.x;
    const int w = tid >> 6, l = tid & 63;
    const int lane15 = l & 15, quad = l >> 4;
    const int wm = (w >> 2) * 128;           // wave M offset (0 or 128)
    const int wn = (w & 3) * 64;             // wave N offset

    // XCD-aware bijective swizzle (both grids are multiples of 8 blocks)
    const int nbn = gridDim.x;
    const int nwg = nbn * gridDim.y;
    const int lid = blockIdx.y * nbn + blockIdx.x;
    const int sid = (lid & 7) * (nwg >> 3) + (lid >> 3);
    const int bn = sid % nbn, bm = sid / nbn;

    const int sr = tid >> 3;     // staged row within 64-row line
    const int sc = tid & 7;      // 16B slot within 128B row
    const int srcswz = (sc ^ (sr & 7)) * 16;   // involution w/ read-side XOR

    // one staging "line" = 64 rows x 64 cols bf16 = 8KB = one gl2lds16/thread
    auto stA = [&](int buf, int t, int ln) {
        int gr = bm * 256 + ln * 64 + sr;
        size_t e;
        if constexpr (MODE == 2)
            e = (size_t)(gr >> 11) * 2097152 + (size_t)t * 131072
                + (size_t)(gr & (TT - 1)) * 64;
        else
            e = (size_t)gr * (size_t)Kd + (size_t)t * 64;
        gl2lds16((const char*)(A + e) + srcswz,
                 (char*)&As[buf][0] + ln * 8192 + tid * 16);
    };
    auto stB = [&](int buf, int t, int ln) {
        int gr = bn * 256 + ln * 64 + sr;
        size_t e = (size_t)gr * (size_t)Kd + (size_t)t * 64;
        gl2lds16((const char*)(Bt + e) + srcswz,
                 (char*)&Bs[buf][0] + ln * 8192 + tid * 16);
    };

    f32x4 acc[8][4];
    #pragma unroll
    for (int m = 0; m < 8; ++m)
        #pragma unroll
        for (int n = 0; n < 4; ++n)
            acc[m][n] = f32x4{0.f, 0.f, 0.f, 0.f};

    // prologue: tile 0 (A+B, 8 loads) + tile 1's B (4 loads); wait tile 0
    stA(0, 0, 0); stA(0, 0, 1); stA(0, 0, 2); stA(0, 0, 3);
    stB(0, 0, 0); stB(0, 0, 1); stB(0, 0, 2); stB(0, 0, 3);
    stB(1, 1, 0); stB(1, 1, 1); stB(1, 1, 2); stB(1, 1, 3);
    waitvm<4>();
    BARF();

    const int swz = (lane15 & 7) << 4;   // read-side XOR (row&7 == lane15&7)
    bf16x8 aR[4][2];        // current m-half: [m-sub][kk]
    bf16x8 bR[4][2];        // all 4 n-frags:  [n][kk]

#define LDA_H(P, MH)                                                          \
    { _Pragma("unroll") for (int i = 0; i < 4; ++i)                           \
      _Pragma("unroll") for (int kk = 0; kk < 2; ++kk)                        \
        aR[i][kk] = *(const bf16x8*)((const char*)&As[P][0] +                 \
            (wm + MH * 64 + i * 16 + lane15) * 128 +                          \
            ((kk * 64 + quad * 16) ^ swz)); }

#define LDB_H(P, NHF)                                                         \
    { _Pragma("unroll") for (int j = 0; j < 2; ++j)                           \
      _Pragma("unroll") for (int kk = 0; kk < 2; ++kk)                        \
        bR[NHF * 2 + j][kk] = *(const bf16x8*)((const char*)&Bs[P][0] +       \
            (wn + (NHF * 2 + j) * 16 + lane15) * 128 +                        \
            ((kk * 64 + quad * 16) ^ swz)); }

#define MFMA_Q(MH, NHF)                                                       \
    { __builtin_amdgcn_s_setprio(1);                                          \
      _Pragma("unroll") for (int kk = 0; kk < 2; ++kk)                        \
      _Pragma("unroll") for (int i = 0; i < 4; ++i)                           \
      _Pragma("unroll") for (int j = 0; j < 2; ++j)                           \
        acc[MH * 4 + i][NHF * 2 + j] =                                        \
            __builtin_amdgcn_mfma_f32_16x16x32_bf16(                          \
                aR[i][kk], bR[NHF * 2 + j][kk], acc[MH * 4 + i][NHF * 2 + j], \
                0, 0, 0);                                                     \
      __builtin_amdgcn_s_setprio(0); }

    for (int t = 0; t < NK; ++t) {
        const int p = t & 1;
        const bool s1 = (t + 1 < NK), s2 = (t + 2 < NK);
        // ---- ph1: quadrant (m0, n0) + stage A(t+1) h0 -> buf p^1 ----
        LDA_H(p, 0);
        LDB_H(p, 0);
        if (s1) { stA(p ^ 1, t + 1, 0); stA(p ^ 1, t + 1, 1); }
        BARF(); LGK0();
        MFMA_Q(0, 0);
        BARF();
        // ---- ph2: quadrant (m0, n1) + stage A(t+1) h1 ----
        LDB_H(p, 1);
        if (s1) { stA(p ^ 1, t + 1, 2); stA(p ^ 1, t + 1, 3); }
        BARF(); LGK0();
        MFMA_Q(0, 1);
        BARF();
        // ---- ph3: quadrant (m1, n1) + stage B(t+2) h0 -> buf p ----
        LDA_H(p, 1);
        if (s2) { stB(p, t + 2, 0); stB(p, t + 2, 1); }
        BARF(); LGK0();
        MFMA_Q(1, 1);
        BARF();
        // ---- ph4: quadrant (m1, n0), no ds-reads; stage B(t+2) h1 ----
        if (s2) { stB(p, t + 2, 2); stB(p, t + 2, 3); }
        MFMA_Q(1, 0);
        if (s1) {
            if (s2) waitvm<4>();   // tile t+1 landed; B(t+2) in flight
            else    waitvm<0>();
            BARF();
        }
    }
#undef LDA_H
#undef LDB_H
#undef MFMA_Q

    if constexpr (MODE == 1) {
        const float SCQ = 0.125f * 1.4426950408889634f;   // folded into Q
        const int colbase = bn * 256 + wn;          // multiple of 64
        const int seg = colbase >> 10;              // 0=q 1=k 2=v (block-unif)
        const int h = (colbase & 1023) >> 6;        // head
        if (seg == 2) {
            // ---- fused V transpose: acc -> LDS [64 d][32 t] (pitch 40,
            // 80B rows: 16B-aligned b128 reads) -> VbT[bh][d][t] coalesced.
            // Per-wave scratch 5120B, disjoint (waves 0-3 in As, 4-7 in Bs);
            // seg is block-uniform so all waves take this path together.
            __syncthreads();   // all waves done reading As/Bs (K-loop)
            ushort_t* scr = ((w & 4) ? &Bs[0][0] : &As[0][0]) + (w & 3) * 2560;
            const int t0 = bm * 256 + wm;            // wave's first row (global)
            const int bq = t0 >> 11;                 // batch (const per wave)
            const int tb = t0 & (TT - 1);            // batch-LOCAL first t (r7 fix)
            const size_t obase = (size_t)(bq * NH + h) * (TT * HD);
            #pragma unroll
            for (int hp = 0; hp < 4; ++hp) {         // 32 t per pass
                #pragma unroll
                for (int mp = 0; mp < 2; ++mp) {
                    int m = hp * 2 + mp;
                    #pragma unroll
                    for (int n = 0; n < 4; ++n) {
                        u16x4 v;
                        v[0] = f2bf(acc[m][n][0]);
                        v[1] = f2bf(acc[m][n][1]);
                        v[2] = f2bf(acc[m][n][2]);
                        v[3] = f2bf(acc[m][n][3]);
                        // d = n*16+lane15, tloc = mp*16 + quad*4 (+r packed)
                        *(u16x4*)&scr[(n * 16 + lane15) * 40 +
                                      mp * 16 + quad * 4] = v;
                    }
                }
                LGK0();                               // own-wave writes visible
                __builtin_amdgcn_sched_barrier(0);
                #pragma unroll
                for (int i = 0; i < 4; ++i) {
                    int dd = i * 16 + (l >> 2);       // 16 d per iter
                    int tl = (l & 3) * 8;             // 8-t chunk
                    ushort8 vv = *(const ushort8*)&scr[dd * 40 + tl];
                    *(ushort8*)(VbT + obase + (size_t)dd * TT +
                                tb + hp * 32 + tl) = vv;
                }
                if (hp < 3) { LGK0(); __builtin_amdgcn_sched_barrier(0); }
            }
        } else {
            ushort_t* dst = (seg == 0) ? Qb : Kb;
            #pragma unroll
            for (int m = 0; m < 8; ++m) {
                int row0 = bm * 256 + wm + m * 16 + quad * 4;
                #pragma unroll
                for (int r = 0; r < 4; ++r) {
                    int row = row0 + r;
                    int b = row >> 11, t = row & (TT - 1);
                    size_t ob = ((size_t)(b * NH + h) * TT + t) * HD;
                    #pragma unroll
                    for (int n = 0; n < 2; ++n) {
                        int j = n * 16 + lane15;        // 0..31
                        float2 cs = rope[t * 32 + j];
                        float x1 = acc[m][n][r];        // d = j
                        float x2 = acc[m][n + 2][r];    // d = j+32
                        float y1 = x1 * cs.x - x2 * cs.y;
                        float y2 = x2 * cs.x + x1 * cs.y;
                        if (seg == 0) { y1 *= SCQ; y2 *= SCQ; }
                        dst[ob + j]      = f2bf(y1);
                        dst[ob + 32 + j] = f2bf(y2);
                    }
                }
            }
        }
    } else {
        #pragma unroll
        for (int m = 0; m < 8; ++m) {
            #pragma unroll
            for (int r = 0; r < 4; ++r) {
                size_t rb = (size_t)(bm * 256 + wm + m * 16 + quad * 4 + r) * N
                            + bn * 256 + wn;
                #pragma unroll
                for (int n = 0; n < 4; ++n)
                    CoutF[rb + n * 16 + lane15] = acc[m][n][r];
            }
        }
    }
}

// ---------------- flash attention (causal), O in place over Q --------------
// grid: (16 q-tiles, B*NH) = 1024 blocks, all co-resident (4/CU).
// XCD-clustered remap: XCD d&7 owns heads [xcd*8, xcd*8+8) (K/V L2 reuse,
// proven -4.4x FETCH). qt permuted via nibble table so stride-32 CU-cohorts
// {p[x],p[x+4],p[x+8],p[x+12]} each sum to 30 -> balanced per-CU work.
// S^T = K*Q^T: S^T's C-frag (kcol=quad*4+reg, qrow=lane15) IS the A-operand
// layout of mfma_16x16x16_bf16 -> P never touches LDS. Q pre-scaled by
// scale*log2e in GEMM1, so scores are already in the exp2 domain.
// Shuffle-free steady state: defer-max checked on IN-LANE partial max only
// (exact as a bound test); row-sum l via ones-column MFMA (C-frag domain,
// same layout as o -> epilogue needs no broadcast). Single barrier per
// k-tile via double-buffered K/V LDS.
__global__ __launch_bounds__(512, 4) void attn_kernel(
    ushort_t* __restrict__ Qb, const ushort_t* __restrict__ Kb,
    const ushort_t* __restrict__ VbT) {
    __shared__ __attribute__((aligned(16))) ushort_t Ks[2][64 * 72]; // K [t][d]
    __shared__ __attribute__((aligned(16))) ushort_t Vs[2][64 * 72]; // V^T [d][t]

    const int tid = threadIdx.x;
    const int w = tid >> 6, l = tid & 63;
    const int lane15 = l & 15, quad = l >> 4;

    const int d = blockIdx.y * gridDim.x + blockIdx.x;
    const int xcd = d & 7, j = d >> 3;
    const int bh = xcd * 8 + (j & 7);
    // qt perm: {15,14,13,12, 0,1,2,3, 11,10,9,8, 4,5,6,7} (nibbles, i=0 low)
    const int qt = (int)((0x765489AB3210CDEFull >> (4 * (j >> 3))) & 15);
    const size_t base = (size_t)bh * (TT * HD);

    const int sr = tid >> 3;         // staging row 0..63
    const int sd = (tid & 7) * 8;    // staging col (elems), 16B per thread
    const ushort_t* kgb = Kb  + base + (size_t)sr * HD + sd;   // + kt*64*HD
    const ushort_t* vgb = VbT + base + (size_t)sr * TT + sd;   // + kt*64

    const int q0 = qt * 128;
    const int rbase = q0 + w * 16;     // wave owns 16 q-rows
    const int ktmax = 2 * qt + 1;      // >= 1 always

    // Q fragments (B-operand of S^T: n=lane15->qrow, k=quad*8+j->dim)
    bf16x8 qf0, qf1;
    {
        const ushort_t* qp = Qb + base + (size_t)(rbase + lane15) * HD + quad * 8;
        qf0 = *(const bf16x8*)qp;
        qf1 = *(const bf16x8*)(qp + 32);
    }

    f32x4 o[4];
    #pragma unroll
    for (int nt = 0; nt < 4; nt++) o[nt] = f32x4{0.f, 0.f, 0.f, 0.f};
    f32x4 lacc = f32x4{0.f, 0.f, 0.f, 0.f};   // row-sum, C-frag domain
    float mrow = -INFINITY;                    // per qrow=lane15

    const s16x4 ONES = {(short)0x3F80, (short)0x3F80,
                        (short)0x3F80, (short)0x3F80};   // bf16 1.0 x4

    // prologue: tile 0 -> buf0; tile 1 -> regs
    ushort8 kr = *(const ushort8*)kgb;
    ushort8 vr = *(const ushort8*)vgb;
    *(ushort8*)&Ks[0][sr * 72 + sd] = kr;
    *(ushort8*)&Vs[0][sr * 72 + sd] = vr;
    kr = *(const ushort8*)(kgb + (size_t)64 * HD);
    vr = *(const ushort8*)(vgb + 64);
    __syncthreads();

    for (int kt = 0; kt <= ktmax; kt++) {
        const int buf = kt & 1;
        // at loop top kr/vr hold tile kt+1; write it to the other buffer
        // (its previous readers finished before the end-of-iter barrier)
        if (kt < ktmax) {
            *(ushort8*)&Ks[buf ^ 1][sr * 72 + sd] = kr;
            *(ushort8*)&Vs[buf ^ 1][sr * 72 + sd] = vr;
        }
        if (kt + 2 <= ktmax) {   // prefetch tile kt+2; overlaps compute
            kr = *(const ushort8*)(kgb + (size_t)(kt + 2) * 64 * HD);
            vr = *(const ushort8*)(vgb + (size_t)(kt + 2) * 64);
        }

        // waves 0-3's last tile can be fully causally masked: skip compute
        // (wave-uniform guard; the barrier below stays outside it)
        if (kt * 64 <= rbase + 15) {
            // S^T tiles: D[kcol][qrow], kcol=c*16+quad*4+reg, qrow=lane15
            f32x4 s[4];
            #pragma unroll
            for (int c = 0; c < 4; c++) {
                bf16x8 k0 = *(const bf16x8*)&Ks[buf][(c * 16 + lane15) * 72 + quad * 8];
                bf16x8 k1 = *(const bf16x8*)&Ks[buf][(c * 16 + lane15) * 72 + 32 + quad * 8];
                f32x4 z = f32x4{0.f, 0.f, 0.f, 0.f};
                z = __builtin_amdgcn_mfma_f32_16x16x32_bf16(k0, qf0, z, 0, 0, 0);
                s[c] = __builtin_amdgcn_mfma_f32_16x16x32_bf16(k1, qf1, z, 0, 0, 0);
            }

            const int qrow = rbase + lane15;
            if (kt * 64 + 63 > rbase) {   // masking needed (wave-uniform)
                #pragma unroll
                for (int c = 0; c < 4; c++)
                    #pragma unroll
                    for (int r = 0; r < 4; r++)
                        if (kt * 64 + c * 16 + quad * 4 + r > qrow) s[c][r] = -1e9f;
            }

            // in-lane partial max (v_max3 triples: 8 ops)
            float a0 = fmaxf(fmaxf(s[0][0], s[0][1]), s[0][2]);
            float a1 = fmaxf(fmaxf(s[0][3], s[1][0]), s[1][1]);
            float a2 = fmaxf(fmaxf(s[1][2], s[1][3]), s[2][0]);
            float a3 = fmaxf(fmaxf(s[2][1], s[2][2]), s[2][3]);
            float a4 = fmaxf(fmaxf(s[3][0], s[3][1]), s[3][2]);
            float mt = fmaxf(fmaxf(a0, a1), a2);
            mt = fmaxf(fmaxf(mt, a3), fmaxf(a4, s[3][3]));

            // defer-max: partial <= bound for all lanes  <=>  row max <= bound
            if (!__all(mt - mrow <= 8.0f)) {
                float mf = fmaxf(mt, __shfl_xor(mt, 16, 64));
                mf = fmaxf(mf, __shfl_xor(mf, 32, 64));
                float mn = fmaxf(mrow, mf);
                float alpha = __builtin_amdgcn_exp2f(mrow - mn);
                mrow = mn;
                #pragma unroll
                for (int r = 0; r < 4; r++) {
                    float aO = __shfl(alpha, quad * 4 + r, 64);
                    #pragma unroll
                    for (int nt = 0; nt < 4; nt++) o[nt][r] *= aO;
                    lacc[r] *= aO;
                }
            }

            // P A-frags (m->qrow, k=quad*4+j->kcol) == S^T C-frag; P bounded
            // by 2^8 (defer). l accumulates P via ones-column MFMA.
            #pragma unroll
            for (int c = 0; c < 4; c++) {
                s16x4 pf;
                #pragma unroll
                for (int r = 0; r < 4; r++)
                    pf[r] = (short)f2bf(__builtin_amdgcn_exp2f(s[c][r] - mrow));
                lacc = __builtin_amdgcn_mfma_f32_16x16x16bf16_1k(
                    pf, ONES, lacc, 0, 0, 0);
                #pragma unroll
                for (int nt = 0; nt < 4; nt++) {
                    s16x4 vf = *(const s16x4*)&Vs[buf][(nt * 16 + lane15) * 72 +
                                                      c * 16 + quad * 4];
                    o[nt] = __builtin_amdgcn_mfma_f32_16x16x16bf16_1k(
                        pf, vf, o[nt], 0, 0, 0);
                }
            }
        }

        if (kt < ktmax) __syncthreads();   // release buf^1 writers / buf readers
    }

    // epilogue: O in place over this wave's Q rows (head-major); l is in the
    // same C-frag domain as o -> no broadcast needed
    #pragma unroll
    for (int r = 0; r < 4; r++) {
        float lO = 1.0f / lacc[r];
        size_t rb = base + (size_t)(rbase + quad * 4 + r) * HD;
        #pragma unroll
        for (int nt = 0; nt < 4; nt++)
            Qb[rb + nt * 16 + lane15] = f2bf(o[nt][r] * lO);
    }
}

// ---------------- launch ----------------
extern "C" void kernel_launch(void* const* d_in, const int* in_sizes, int n_in,
                              void* d_out, int out_size, void* d_ws, size_t ws_size,
                              hipStream_t stream) {
    const float* x    = (const float*)d_in[0];   // [8192][1024] fp32
    const float* wqkv = (const float*)d_in[1];   // [1024][3072] fp32
    const float* wout = (const float*)d_in[2];   // [1024][1024] fp32
    float* out = (float*)d_out;                  // [8192][1024] fp32

    // ws layout (72.5 MiB total):
    char* ws = (char*)d_ws;
    ushort_t* WqkvT = (ushort_t*)(ws);                        // [3072][1024] bf16
    ushort_t* WoutT = (ushort_t*)(ws + 6291456);              // [1024][1024] bf16
    float2*   rope  = (float2*)  (ws + 8388608);              // [2048*32]
    ushort_t* Xb    = (ushort_t*)(ws + 8912896);              // [8192][1024] bf16
    ushort_t* Qb    = (ushort_t*)(ws + 8912896 + 16777216);   // [64][2048][64]
    ushort_t* Kb    = (ushort_t*)(ws + 8912896 + 2 * 16777216);
    ushort_t* VbT   = (ushort_t*)(ws + 8912896 + 3 * 16777216); // [64][64][2048]
    // V is written directly transposed by GEMM1's epilogue (vtrans fused).

    cvt_f32_bf16<<<dim3(MM * CC / (256 * 8)), 256, 0, stream>>>(x, Xb);
    transpose_f2b<<<dim3(3 * CC / 32, CC / 32), 256, 0, stream>>>(wqkv, WqkvT, CC, 3 * CC);
    transpose_f2b<<<dim3(CC / 32, CC / 32), 256, 0, stream>>>(wout, WoutT, CC, CC);
    rope_table<<<dim3(256), 256, 0, stream>>>(rope);

    // 256x256 tiles: grid1 = 12x32 = 384 blocks, grid2 = 4x32 = 128 blocks;
    // both %8==0 for XCD swizzle.
    gemm_bt<1><<<dim3(3 * CC / 256, MM / 256), 512, 0, stream>>>(
        Xb, WqkvT, nullptr, Qb, Kb, VbT, rope, MM, 3 * CC, CC);

    attn_kernel<<<dim3(16, BB * NH), 512, 0, stream>>>(Qb, Kb, VbT);

    gemm_bt<2><<<dim3(CC / 256, MM / 256), 512, 0, stream>>>(
        Qb, WoutT, out, nullptr, nullptr, nullptr, nullptr, MM, CC, CC);
}

// Round 9
// 250.605 us; speedup vs baseline: 1.0998x; 1.0133x over previous
//
#include <hip/hip_runtime.h>
#include <stdint.h>

#define DEVI __device__ __forceinline__

typedef unsigned short ushort_t;
typedef __bf16 bf16x8 __attribute__((ext_vector_type(8)));
typedef float f32x4 __attribute__((ext_vector_type(4)));
typedef unsigned short ushort8 __attribute__((ext_vector_type(8)));
typedef unsigned short u16x4 __attribute__((ext_vector_type(4)));
typedef short s16x4 __attribute__((ext_vector_type(4)));

// ---- constants ----
#define BB 4
#define TT 2048
#define CC 1024
#define NH 16
#define HD 64
#define MM (BB*TT)          // 8192

// native RNE f32->bf16 (compiler pairs into v_cvt_pk_bf16_f32; m240)
DEVI ushort_t f2bf(float f) {
    __bf16 h = (__bf16)f;
    return __builtin_bit_cast(ushort_t, h);
}

typedef const __attribute__((address_space(1))) unsigned int guint_t;
typedef __attribute__((address_space(3))) unsigned int luint_t;

// async global->LDS, 16B/lane; lds dest is wave-uniform base + lane*16
DEVI void gl2lds16(const void* g, void* lds) {
    __builtin_amdgcn_global_load_lds((guint_t*)(uintptr_t)g,
                                     (luint_t*)(unsigned int)(uintptr_t)lds,
                                     16, 0, 0);
}

template <int N> DEVI void waitvm() {
    static_assert(N == 0 || N == 4, "unsupported vmcnt literal");
    if constexpr (N == 0)      asm volatile("s_waitcnt vmcnt(0)" ::: "memory");
    else if constexpr (N == 4) asm volatile("s_waitcnt vmcnt(4)" ::: "memory");
}

#define BARF() do { asm volatile("" ::: "memory"); \
                    __builtin_amdgcn_s_barrier(); \
                    asm volatile("" ::: "memory"); } while (0)
#define LGK0() asm volatile("s_waitcnt lgkmcnt(0)" ::: "memory")

// ---------------- fp32 -> bf16 bulk convert (8 elems/thread) ----------------
__global__ void cvt_f32_bf16(const float* __restrict__ in,
                             ushort_t* __restrict__ out) {
    int i = blockIdx.x * 256 + threadIdx.x;
    const float4* p = (const float4*)in + (size_t)i * 2;
    float4 a = p[0], b = p[1];
    ushort8 r;
    r[0] = f2bf(a.x); r[1] = f2bf(a.y); r[2] = f2bf(a.z); r[3] = f2bf(a.w);
    r[4] = f2bf(b.x); r[5] = f2bf(b.y); r[6] = f2bf(b.z); r[7] = f2bf(b.w);
    *(ushort8*)(out + (size_t)i * 8) = r;
}

// ------------- transpose fp32 -> bf16: in[R][Cc] -> out[Cc][R] -------------
__global__ void transpose_f2b(const float* __restrict__ in,
                              ushort_t* __restrict__ out, int R, int Cc) {
    __shared__ ushort_t tile[32][33];
    int bx = blockIdx.x * 32;
    int by = blockIdx.y * 32;
    int tx = threadIdx.x & 31, ty = threadIdx.x >> 5;
    #pragma unroll
    for (int i = 0; i < 4; i++) {
        int r = ty * 4 + i;
        tile[r][tx] = f2bf(in[(size_t)(by + r) * Cc + bx + tx]);
    }
    __syncthreads();
    #pragma unroll
    for (int i = 0; i < 4; i++) {
        int r = ty * 4 + i;
        out[(size_t)(bx + r) * R + by + tx] = tile[tx][r];
    }
}

// ---------------- rope table: tab[t*32+j] = (cos, sin) ----------------
__global__ void rope_table(float2* __restrict__ tab) {
    int i = blockIdx.x * 256 + threadIdx.x;   // 65536 total
    int t = i >> 5, j = i & 31;
    float inv = exp2f((float)j * -0.41524101186092029f);
    float theta = (float)t * inv;
    float s, c;
    sincosf(theta, &s, &c);
    tab[i] = make_float2(c, s);
}

// ---------------- GEMM: C = A * Bt^T  (A,Bt bf16) --------------------------
// 256x256 tile, BK=64, 512 threads = 8 waves (2M x 4N), per-wave output
// 128x64 (acc[8][4]), LDS 128 KiB double-buffered, 4 phases/K-tile with
// counted vmcnt(4) (unchanged from r5 — best GEMM so far).
// MODE 1: A=[M][Kd] row-major; epilogue: rope q,k (q pre-scaled by
//         scale*log2e) scatter to [B*NH][T][HD]; V written DIRECTLY
//         TRANSPOSED to VbT[bh][d][t] via per-wave LDS round-trip.
// MODE 2: A head-major [(b*16+h)*2048+t][64]; fp32 store to CoutF[M][N]
template <int MODE>
__global__ __launch_bounds__(512, 2) void gemm_bt(
    const ushort_t* __restrict__ A, const ushort_t* __restrict__ Bt,
    float* __restrict__ CoutF,
    ushort_t* __restrict__ Qb, ushort_t* __restrict__ Kb, ushort_t* __restrict__ VbT,
    const float2* __restrict__ rope, int M, int N, int Kd) {
    constexpr int NK = CC / 64;      // 16 K-tiles (Kd == 1024 for both GEMMs)
    (void)M;

    __shared__ __attribute__((aligned(16))) ushort_t As[2][256 * 64];  // 64 KiB
    __shared__ __attribute__((aligned(16))) ushort_t Bs[2][256 * 64];  // 64 KiB

    const int tid = threadIdx.x;
    const int w = tid >> 6, l = tid & 63;
    const int lane15 = l & 15, quad = l >> 4;
    const int wm = (w >> 2) * 128;           // wave M offset (0 or 128)
    const int wn = (w & 3) * 64;             // wave N offset

    // XCD-aware bijective swizzle (both grids are multiples of 8 blocks)
    const int nbn = gridDim.x;
    const int nwg = nbn * gridDim.y;
    const int lid = blockIdx.y * nbn + blockIdx.x;
    const int sid = (lid & 7) * (nwg >> 3) + (lid >> 3);
    const int bn = sid % nbn, bm = sid / nbn;

    const int sr = tid >> 3;     // staged row within 64-row line
    const int sc = tid & 7;      // 16B slot within 128B row
    const int srcswz = (sc ^ (sr & 7)) * 16;   // involution w/ read-side XOR

    // one staging "line" = 64 rows x 64 cols bf16 = 8KB = one gl2lds16/thread
    auto stA = [&](int buf, int t, int ln) {
        int gr = bm * 256 + ln * 64 + sr;
        size_t e;
        if constexpr (MODE == 2)
            e = (size_t)(gr >> 11) * 2097152 + (size_t)t * 131072
                + (size_t)(gr & (TT - 1)) * 64;
        else
            e = (size_t)gr * (size_t)Kd + (size_t)t * 64;
        gl2lds16((const char*)(A + e) + srcswz,
                 (char*)&As[buf][0] + ln * 8192 + tid * 16);
    };
    auto stB = [&](int buf, int t, int ln) {
        int gr = bn * 256 + ln * 64 + sr;
        size_t e = (size_t)gr * (size_t)Kd + (size_t)t * 64;
        gl2lds16((const char*)(Bt + e) + srcswz,
                 (char*)&Bs[buf][0] + ln * 8192 + tid * 16);
    };

    f32x4 acc[8][4];
    #pragma unroll
    for (int m = 0; m < 8; ++m)
        #pragma unroll
        for (int n = 0; n < 4; ++n)
            acc[m][n] = f32x4{0.f, 0.f, 0.f, 0.f};

    // prologue: tile 0 (A+B, 8 loads) + tile 1's B (4 loads); wait tile 0
    stA(0, 0, 0); stA(0, 0, 1); stA(0, 0, 2); stA(0, 0, 3);
    stB(0, 0, 0); stB(0, 0, 1); stB(0, 0, 2); stB(0, 0, 3);
    stB(1, 1, 0); stB(1, 1, 1); stB(1, 1, 2); stB(1, 1, 3);
    waitvm<4>();
    BARF();

    const int swz = (lane15 & 7) << 4;   // read-side XOR (row&7 == lane15&7)
    bf16x8 aR[4][2];        // current m-half: [m-sub][kk]
    bf16x8 bR[4][2];        // all 4 n-frags:  [n][kk]

#define LDA_H(P, MH)                                                          \
    { _Pragma("unroll") for (int i = 0; i < 4; ++i)                           \
      _Pragma("unroll") for (int kk = 0; kk < 2; ++kk)                        \
        aR[i][kk] = *(const bf16x8*)((const char*)&As[P][0] +                 \
            (wm + MH * 64 + i * 16 + lane15) * 128 +                          \
            ((kk * 64 + quad * 16) ^ swz)); }

#define LDB_H(P, NHF)                                                         \
    { _Pragma("unroll") for (int j = 0; j < 2; ++j)                           \
      _Pragma("unroll") for (int kk = 0; kk < 2; ++kk)                        \
        bR[NHF * 2 + j][kk] = *(const bf16x8*)((const char*)&Bs[P][0] +       \
            (wn + (NHF * 2 + j) * 16 + lane15) * 128 +                        \
            ((kk * 64 + quad * 16) ^ swz)); }

#define MFMA_Q(MH, NHF)                                                       \
    { __builtin_amdgcn_s_setprio(1);                                          \
      _Pragma("unroll") for (int kk = 0; kk < 2; ++kk)                        \
      _Pragma("unroll") for (int i = 0; i < 4; ++i)                           \
      _Pragma("unroll") for (int j = 0; j < 2; ++j)                           \
        acc[MH * 4 + i][NHF * 2 + j] =                                        \
            __builtin_amdgcn_mfma_f32_16x16x32_bf16(                          \
                aR[i][kk], bR[NHF * 2 + j][kk], acc[MH * 4 + i][NHF * 2 + j], \
                0, 0, 0);                                                     \
      __builtin_amdgcn_s_setprio(0); }

    for (int t = 0; t < NK; ++t) {
        const int p = t & 1;
        const bool s1 = (t + 1 < NK), s2 = (t + 2 < NK);
        // ---- ph1: quadrant (m0, n0) + stage A(t+1) h0 -> buf p^1 ----
        LDA_H(p, 0);
        LDB_H(p, 0);
        if (s1) { stA(p ^ 1, t + 1, 0); stA(p ^ 1, t + 1, 1); }
        BARF(); LGK0();
        MFMA_Q(0, 0);
        BARF();
        // ---- ph2: quadrant (m0, n1) + stage A(t+1) h1 ----
        LDB_H(p, 1);
        if (s1) { stA(p ^ 1, t + 1, 2); stA(p ^ 1, t + 1, 3); }
        BARF(); LGK0();
        MFMA_Q(0, 1);
        BARF();
        // ---- ph3: quadrant (m1, n1) + stage B(t+2) h0 -> buf p ----
        LDA_H(p, 1);
        if (s2) { stB(p, t + 2, 0); stB(p, t + 2, 1); }
        BARF(); LGK0();
        MFMA_Q(1, 1);
        BARF();
        // ---- ph4: quadrant (m1, n0), no ds-reads; stage B(t+2) h1 ----
        if (s2) { stB(p, t + 2, 2); stB(p, t + 2, 3); }
        MFMA_Q(1, 0);
        if (s1) {
            if (s2) waitvm<4>();   // tile t+1 landed; B(t+2) in flight
            else    waitvm<0>();
            BARF();
        }
    }
#undef LDA_H
#undef LDB_H
#undef MFMA_Q

    if constexpr (MODE == 1) {
        const float SCQ = 0.125f * 1.4426950408889634f;   // folded into Q
        const int colbase = bn * 256 + wn;          // multiple of 64
        const int seg = colbase >> 10;              // 0=q 1=k 2=v (block-unif)
        const int h = (colbase & 1023) >> 6;        // head
        if (seg == 2) {
            // ---- fused V transpose: acc -> LDS [64 d][32 t] (pitch 40,
            // 80B rows: 16B-aligned b128 reads) -> VbT[bh][d][t] coalesced.
            // Per-wave scratch 5120B, disjoint (waves 0-3 in As, 4-7 in Bs);
            // seg is block-uniform so all waves take this path together.
            __syncthreads();   // all waves done reading As/Bs (K-loop)
            ushort_t* scr = ((w & 4) ? &Bs[0][0] : &As[0][0]) + (w & 3) * 2560;
            const int t0 = bm * 256 + wm;            // wave's first row (global)
            const int bq = t0 >> 11;                 // batch (const per wave)
            const int tb = t0 & (TT - 1);            // batch-LOCAL first t (r7 fix)
            const size_t obase = (size_t)(bq * NH + h) * (TT * HD);
            #pragma unroll
            for (int hp = 0; hp < 4; ++hp) {         // 32 t per pass
                #pragma unroll
                for (int mp = 0; mp < 2; ++mp) {
                    int m = hp * 2 + mp;
                    #pragma unroll
                    for (int n = 0; n < 4; ++n) {
                        u16x4 v;
                        v[0] = f2bf(acc[m][n][0]);
                        v[1] = f2bf(acc[m][n][1]);
                        v[2] = f2bf(acc[m][n][2]);
                        v[3] = f2bf(acc[m][n][3]);
                        // d = n*16+lane15, tloc = mp*16 + quad*4 (+r packed)
                        *(u16x4*)&scr[(n * 16 + lane15) * 40 +
                                      mp * 16 + quad * 4] = v;
                    }
                }
                LGK0();                               // own-wave writes visible
                __builtin_amdgcn_sched_barrier(0);
                #pragma unroll
                for (int i = 0; i < 4; ++i) {
                    int dd = i * 16 + (l >> 2);       // 16 d per iter
                    int tl = (l & 3) * 8;             // 8-t chunk
                    ushort8 vv = *(const ushort8*)&scr[dd * 40 + tl];
                    *(ushort8*)(VbT + obase + (size_t)dd * TT +
                                tb + hp * 32 + tl) = vv;
                }
                if (hp < 3) { LGK0(); __builtin_amdgcn_sched_barrier(0); }
            }
        } else {
            ushort_t* dst = (seg == 0) ? Qb : Kb;
            #pragma unroll
            for (int m = 0; m < 8; ++m) {
                int row0 = bm * 256 + wm + m * 16 + quad * 4;
                #pragma unroll
                for (int r = 0; r < 4; ++r) {
                    int row = row0 + r;
                    int b = row >> 11, t = row & (TT - 1);
                    size_t ob = ((size_t)(b * NH + h) * TT + t) * HD;
                    #pragma unroll
                    for (int n = 0; n < 2; ++n) {
                        int j = n * 16 + lane15;        // 0..31
                        float2 cs = rope[t * 32 + j];
                        float x1 = acc[m][n][r];        // d = j
                        float x2 = acc[m][n + 2][r];    // d = j+32
                        float y1 = x1 * cs.x - x2 * cs.y;
                        float y2 = x2 * cs.x + x1 * cs.y;
                        if (seg == 0) { y1 *= SCQ; y2 *= SCQ; }
                        dst[ob + j]      = f2bf(y1);
                        dst[ob + 32 + j] = f2bf(y2);
                    }
                }
            }
        }
    } else {
        #pragma unroll
        for (int m = 0; m < 8; ++m) {
            #pragma unroll
            for (int r = 0; r < 4; ++r) {
                size_t rb = (size_t)(bm * 256 + wm + m * 16 + quad * 4 + r) * N
                            + bn * 256 + wn;
                #pragma unroll
                for (int n = 0; n < 4; ++n)
                    CoutF[rb + n * 16 + lane15] = acc[m][n][r];
            }
        }
    }
}

// ---------------- flash attention (causal), O in place over Q --------------
// grid: (16 q-tiles, B*NH) = 1024 blocks, all co-resident (4/CU).
// XCD-clustered remap; qt permuted for per-CU balance.
// S^T = K*Q^T; P never touches LDS; defer-max on in-lane partial; l via
// ones-column MFMA; single barrier per k-tile via double-buffered K/V LDS.
// r9: K/V LDS tiles pitch-64 (128B rows) + byte-involution swizzle
// col ^ ((row&7)<<4) on BOTH write and read sides (T2 recipe, zero-conflict
// verified in the GEMM). Kills the 8-way conflict of the old pitch-72 Ks
// b128 reads (SQ_LDS_BANK_CONFLICT 1.3e7/dispatch).
__global__ __launch_bounds__(512, 4) void attn_kernel(
    ushort_t* __restrict__ Qb, const ushort_t* __restrict__ Kb,
    const ushort_t* __restrict__ VbT) {
    __shared__ __attribute__((aligned(16))) ushort_t Ks[2][64 * 64]; // K [t][d]
    __shared__ __attribute__((aligned(16))) ushort_t Vs[2][64 * 64]; // V^T [d][t]

    const int tid = threadIdx.x;
    const int w = tid >> 6, l = tid & 63;
    const int lane15 = l & 15, quad = l >> 4;

    const int d = blockIdx.y * gridDim.x + blockIdx.x;
    const int xcd = d & 7, j = d >> 3;
    const int bh = xcd * 8 + (j & 7);
    // qt perm: {15,14,13,12, 0,1,2,3, 11,10,9,8, 4,5,6,7} (nibbles, i=0 low)
    const int qt = (int)((0x765489AB3210CDEFull >> (4 * (j >> 3))) & 15);
    const size_t base = (size_t)bh * (TT * HD);

    const int sr = tid >> 3;         // staging row 0..63
    const int sd = (tid & 7) * 8;    // staging col (elems), 16B per thread
    // swizzled byte col for the staging write (involution with read XOR)
    const int scol = (sd * 2) ^ ((sr & 7) << 4);
    const ushort_t* kgb = Kb  + base + (size_t)sr * HD + sd;   // + kt*64*HD
    const ushort_t* vgb = VbT + base + (size_t)sr * TT + sd;   // + kt*64

    const int q0 = qt * 128;
    const int rbase = q0 + w * 16;     // wave owns 16 q-rows
    const int ktmax = 2 * qt + 1;      // >= 1 always

    // Q fragments (B-operand of S^T: n=lane15->qrow, k=quad*8+j->dim)
    bf16x8 qf0, qf1;
    {
        const ushort_t* qp = Qb + base + (size_t)(rbase + lane15) * HD + quad * 8;
        qf0 = *(const bf16x8*)qp;
        qf1 = *(const bf16x8*)(qp + 32);
    }

    f32x4 o[4];
    #pragma unroll
    for (int nt = 0; nt < 4; nt++) o[nt] = f32x4{0.f, 0.f, 0.f, 0.f};
    f32x4 lacc = f32x4{0.f, 0.f, 0.f, 0.f};   // row-sum, C-frag domain
    float mrow = -INFINITY;                    // per qrow=lane15

    const s16x4 ONES = {(short)0x3F80, (short)0x3F80,
                        (short)0x3F80, (short)0x3F80};   // bf16 1.0 x4

    // read-side XOR (row&7 == lane15&7 for all LDS reads below)
    const int rsw = (lane15 & 7) << 4;

    // prologue: tile 0 -> buf0; tile 1 -> regs
    ushort8 kr = *(const ushort8*)kgb;
    ushort8 vr = *(const ushort8*)vgb;
    *(ushort8*)((char*)&Ks[0][0] + sr * 128 + scol) = kr;
    *(ushort8*)((char*)&Vs[0][0] + sr * 128 + scol) = vr;
    kr = *(const ushort8*)(kgb + (size_t)64 * HD);
    vr = *(const ushort8*)(vgb + 64);
    __syncthreads();

    for (int kt = 0; kt <= ktmax; kt++) {
        const int buf = kt & 1;
        // at loop top kr/vr hold tile kt+1; write it to the other buffer
        // (its previous readers finished before the end-of-iter barrier)
        if (kt < ktmax) {
            *(ushort8*)((char*)&Ks[buf ^ 1][0] + sr * 128 + scol) = kr;
            *(ushort8*)((char*)&Vs[buf ^ 1][0] + sr * 128 + scol) = vr;
        }
        if (kt + 2 <= ktmax) {   // prefetch tile kt+2; overlaps compute
            kr = *(const ushort8*)(kgb + (size_t)(kt + 2) * 64 * HD);
            vr = *(const ushort8*)(vgb + (size_t)(kt + 2) * 64);
        }

        // waves 0-3's last tile can be fully causally masked: skip compute
        // (wave-uniform guard; the barrier below stays outside it)
        if (kt * 64 <= rbase + 15) {
            // S^T tiles: D[kcol][qrow], kcol=c*16+quad*4+reg, qrow=lane15
            f32x4 s[4];
            #pragma unroll
            for (int c = 0; c < 4; c++) {
                const char* krow = (const char*)&Ks[buf][0]
                                   + (c * 16 + lane15) * 128;
                bf16x8 k0 = *(const bf16x8*)(krow + ((quad * 16) ^ rsw));
                bf16x8 k1 = *(const bf16x8*)(krow + ((64 + quad * 16) ^ rsw));
                f32x4 z = f32x4{0.f, 0.f, 0.f, 0.f};
                z = __builtin_amdgcn_mfma_f32_16x16x32_bf16(k0, qf0, z, 0, 0, 0);
                s[c] = __builtin_amdgcn_mfma_f32_16x16x32_bf16(k1, qf1, z, 0, 0, 0);
            }

            const int qrow = rbase + lane15;
            if (kt * 64 + 63 > rbase) {   // masking needed (wave-uniform)
                #pragma unroll
                for (int c = 0; c < 4; c++)
                    #pragma unroll
                    for (int r = 0; r < 4; r++)
                        if (kt * 64 + c * 16 + quad * 4 + r > qrow) s[c][r] = -1e9f;
            }

            // in-lane partial max (v_max3 triples: 8 ops)
            float a0 = fmaxf(fmaxf(s[0][0], s[0][1]), s[0][2]);
            float a1 = fmaxf(fmaxf(s[0][3], s[1][0]), s[1][1]);
            float a2 = fmaxf(fmaxf(s[1][2], s[1][3]), s[2][0]);
            float a3 = fmaxf(fmaxf(s[2][1], s[2][2]), s[2][3]);
            float a4 = fmaxf(fmaxf(s[3][0], s[3][1]), s[3][2]);
            float mt = fmaxf(fmaxf(a0, a1), a2);
            mt = fmaxf(fmaxf(mt, a3), fmaxf(a4, s[3][3]));

            // defer-max: partial <= bound for all lanes  <=>  row max <= bound
            if (!__all(mt - mrow <= 8.0f)) {
                float mf = fmaxf(mt, __shfl_xor(mt, 16, 64));
                mf = fmaxf(mf, __shfl_xor(mf, 32, 64));
                float mn = fmaxf(mrow, mf);
                float alpha = __builtin_amdgcn_exp2f(mrow - mn);
                mrow = mn;
                #pragma unroll
                for (int r = 0; r < 4; r++) {
                    float aO = __shfl(alpha, quad * 4 + r, 64);
                    #pragma unroll
                    for (int nt = 0; nt < 4; nt++) o[nt][r] *= aO;
                    lacc[r] *= aO;
                }
            }

            // P A-frags (m->qrow, k=quad*4+j->kcol) == S^T C-frag; P bounded
            // by 2^8 (defer). l accumulates P via ones-column MFMA.
            #pragma unroll
            for (int c = 0; c < 4; c++) {
                s16x4 pf;
                #pragma unroll
                for (int r = 0; r < 4; r++)
                    pf[r] = (short)f2bf(__builtin_amdgcn_exp2f(s[c][r] - mrow));
                lacc = __builtin_amdgcn_mfma_f32_16x16x16bf16_1k(
                    pf, ONES, lacc, 0, 0, 0);
                #pragma unroll
                for (int nt = 0; nt < 4; nt++) {
                    s16x4 vf = *(const s16x4*)((const char*)&Vs[buf][0] +
                        (nt * 16 + lane15) * 128 +
                        ((c * 32 + quad * 8) ^ rsw));
                    o[nt] = __builtin_amdgcn_mfma_f32_16x16x16bf16_1k(
                        pf, vf, o[nt], 0, 0, 0);
                }
            }
        }

        if (kt < ktmax) __syncthreads();   // release buf^1 writers / buf readers
    }

    // epilogue: O in place over this wave's Q rows (head-major); l is in the
    // same C-frag domain as o -> no broadcast needed
    #pragma unroll
    for (int r = 0; r < 4; r++) {
        float lO = 1.0f / lacc[r];
        size_t rb = base + (size_t)(rbase + quad * 4 + r) * HD;
        #pragma unroll
        for (int nt = 0; nt < 4; nt++)
            Qb[rb + nt * 16 + lane15] = f2bf(o[nt][r] * lO);
    }
}

// ---------------- launch ----------------
extern "C" void kernel_launch(void* const* d_in, const int* in_sizes, int n_in,
                              void* d_out, int out_size, void* d_ws, size_t ws_size,
                              hipStream_t stream) {
    const float* x    = (const float*)d_in[0];   // [8192][1024] fp32
    const float* wqkv = (const float*)d_in[1];   // [1024][3072] fp32
    const float* wout = (const float*)d_in[2];   // [1024][1024] fp32
    float* out = (float*)d_out;                  // [8192][1024] fp32

    // ws layout (72.5 MiB total):
    char* ws = (char*)d_ws;
    ushort_t* WqkvT = (ushort_t*)(ws);                        // [3072][1024] bf16
    ushort_t* WoutT = (ushort_t*)(ws + 6291456);              // [1024][1024] bf16
    float2*   rope  = (float2*)  (ws + 8388608);              // [2048*32]
    ushort_t* Xb    = (ushort_t*)(ws + 8912896);              // [8192][1024] bf16
    ushort_t* Qb    = (ushort_t*)(ws + 8912896 + 16777216);   // [64][2048][64]
    ushort_t* Kb    = (ushort_t*)(ws + 8912896 + 2 * 16777216);
    ushort_t* VbT   = (ushort_t*)(ws + 8912896 + 3 * 16777216); // [64][64][2048]
    // V is written directly transposed by GEMM1's epilogue (vtrans fused).

    cvt_f32_bf16<<<dim3(MM * CC / (256 * 8)), 256, 0, stream>>>(x, Xb);
    transpose_f2b<<<dim3(3 * CC / 32, CC / 32), 256, 0, stream>>>(wqkv, WqkvT, CC, 3 * CC);
    transpose_f2b<<<dim3(CC / 32, CC / 32), 256, 0, stream>>>(wout, WoutT, CC, CC);
    rope_table<<<dim3(256), 256, 0, stream>>>(rope);

    // 256x256 tiles: grid1 = 12x32 = 384 blocks, grid2 = 4x32 = 128 blocks;
    // both %8==0 for XCD swizzle.
    gemm_bt<1><<<dim3(3 * CC / 256, MM / 256), 512, 0, stream>>>(
        Xb, WqkvT, nullptr, Qb, Kb, VbT, rope, MM, 3 * CC, CC);

    attn_kernel<<<dim3(16, BB * NH), 512, 0, stream>>>(Qb, Kb, VbT);

    gemm_bt<2><<<dim3(CC / 256, MM / 256), 512, 0, stream>>>(
        Qb, WoutT, out, nullptr, nullptr, nullptr, nullptr, MM, CC, CC);
}

// Round 10
// 241.931 us; speedup vs baseline: 1.1392x; 1.0359x over previous
//
#include <hip/hip_runtime.h>
#include <stdint.h>

#define DEVI __device__ __forceinline__

typedef unsigned short ushort_t;
typedef __bf16 bf16x8 __attribute__((ext_vector_type(8)));
typedef float f32x4 __attribute__((ext_vector_type(4)));
typedef unsigned short ushort8 __attribute__((ext_vector_type(8)));
typedef unsigned short u16x4 __attribute__((ext_vector_type(4)));
typedef short s16x4 __attribute__((ext_vector_type(4)));

// ---- constants ----
#define BB 4
#define TT 2048
#define CC 1024
#define NH 16
#define HD 64
#define MM (BB*TT)          // 8192

// native RNE f32->bf16 (compiler pairs into v_cvt_pk_bf16_f32; m240)
DEVI ushort_t f2bf(float f) {
    __bf16 h = (__bf16)f;
    return __builtin_bit_cast(ushort_t, h);
}

typedef const __attribute__((address_space(1))) unsigned int guint_t;
typedef __attribute__((address_space(3))) unsigned int luint_t;

// async global->LDS, 16B/lane; lds dest is wave-uniform base + lane*16
DEVI void gl2lds16(const void* g, void* lds) {
    __builtin_amdgcn_global_load_lds((guint_t*)(uintptr_t)g,
                                     (luint_t*)(unsigned int)(uintptr_t)lds,
                                     16, 0, 0);
}

template <int N> DEVI void waitvm() {
    static_assert(N == 0 || N == 4, "unsupported vmcnt literal");
    if constexpr (N == 0)      asm volatile("s_waitcnt vmcnt(0)" ::: "memory");
    else if constexpr (N == 4) asm volatile("s_waitcnt vmcnt(4)" ::: "memory");
}

#define BARF() do { asm volatile("" ::: "memory"); \
                    __builtin_amdgcn_s_barrier(); \
                    asm volatile("" ::: "memory"); } while (0)
#define LGK0() asm volatile("s_waitcnt lgkmcnt(0)" ::: "memory")

// ---------------- fused prep: cvt + 2 transposes + rope table --------------
// block ranges: [0,4096) cvt x->Xb; [4096,7168) wqkv^T; [7168,8192) wout^T;
// [8192,8448) rope. One dispatch instead of four (launch-gap reduction).
__global__ __launch_bounds__(256) void prep(
    const float* __restrict__ x, ushort_t* __restrict__ Xb,
    const float* __restrict__ wqkv, ushort_t* __restrict__ WqkvT,
    const float* __restrict__ wout, ushort_t* __restrict__ WoutT,
    float2* __restrict__ rope) {
    __shared__ ushort_t tile[32][33];
    const int b = blockIdx.x, tid = threadIdx.x;
    if (b < 4096) {                       // ---- fp32 -> bf16, 8 elems/thread
        int i = b * 256 + tid;
        const float4* p = (const float4*)x + (size_t)i * 2;
        float4 a = p[0], c = p[1];
        ushort8 r;
        r[0] = f2bf(a.x); r[1] = f2bf(a.y); r[2] = f2bf(a.z); r[3] = f2bf(a.w);
        r[4] = f2bf(c.x); r[5] = f2bf(c.y); r[6] = f2bf(c.z); r[7] = f2bf(c.w);
        *(ushort8*)(Xb + (size_t)i * 8) = r;
    } else if (b < 8192) {                // ---- transpose fp32 -> bf16
        const float* in; ushort_t* out; int Cc, bx, by;
        if (b < 7168) {
            int b2 = b - 4096;            // wqkv [1024][3072] -> [3072][1024]
            in = wqkv; out = WqkvT; Cc = 3 * CC;
            bx = (b2 % 96) * 32; by = (b2 / 96) * 32;
        } else {
            int b3 = b - 7168;            // wout [1024][1024] -> [1024][1024]
            in = wout; out = WoutT; Cc = CC;
            bx = (b3 & 31) * 32; by = (b3 >> 5) * 32;
        }
        int tx = tid & 31, ty = tid >> 5;
        #pragma unroll
        for (int i = 0; i < 4; i++) {
            int r = ty * 4 + i;
            tile[r][tx] = f2bf(in[(size_t)(by + r) * Cc + bx + tx]);
        }
        __syncthreads();
        #pragma unroll
        for (int i = 0; i < 4; i++) {
            int r = ty * 4 + i;
            out[(size_t)(bx + r) * CC + by + tx] = tile[tx][r];
        }
    } else {                              // ---- rope table (65536 entries)
        int i = (b - 8192) * 256 + tid;
        int t = i >> 5, jj = i & 31;
        float inv = exp2f((float)jj * -0.41524101186092029f);
        float theta = (float)t * inv;
        float s, c;
        sincosf(theta, &s, &c);
        rope[i] = make_float2(c, s);
    }
}

// ---------------- GEMM: C = A * Bt^T  (A,Bt bf16) --------------------------
// 256x256 tile, BK=64, 512 threads = 8 waves (2M x 4N), per-wave output
// 128x64 (acc[8][4]), LDS 128 KiB double-buffered, 4 phases/K-tile with
// counted vmcnt(4) (r5 structure — best GEMM so far; unchanged).
// MODE 1: A=[M][Kd] row-major; epilogue: rope q,k (q pre-scaled by
//         scale*log2e) scatter to [B*NH][T][HD]; V written DIRECTLY
//         TRANSPOSED to VbT[bh][d][t] via per-wave LDS round-trip.
// MODE 2: A head-major [(b*16+h)*2048+t][64]; fp32 store to CoutF[M][N]
template <int MODE>
__global__ __launch_bounds__(512, 2) void gemm_bt(
    const ushort_t* __restrict__ A, const ushort_t* __restrict__ Bt,
    float* __restrict__ CoutF,
    ushort_t* __restrict__ Qb, ushort_t* __restrict__ Kb, ushort_t* __restrict__ VbT,
    const float2* __restrict__ rope, int M, int N, int Kd) {
    constexpr int NK = CC / 64;      // 16 K-tiles (Kd == 1024 for both GEMMs)
    (void)M;

    __shared__ __attribute__((aligned(16))) ushort_t As[2][256 * 64];  // 64 KiB
    __shared__ __attribute__((aligned(16))) ushort_t Bs[2][256 * 64];  // 64 KiB

    const int tid = threadIdx.x;
    const int w = tid >> 6, l = tid & 63;
    const int lane15 = l & 15, quad = l >> 4;
    const int wm = (w >> 2) * 128;           // wave M offset (0 or 128)
    const int wn = (w & 3) * 64;             // wave N offset

    // XCD-aware bijective swizzle (both grids are multiples of 8 blocks)
    const int nbn = gridDim.x;
    const int nwg = nbn * gridDim.y;
    const int lid = blockIdx.y * nbn + blockIdx.x;
    const int sid = (lid & 7) * (nwg >> 3) + (lid >> 3);
    const int bn = sid % nbn, bm = sid / nbn;

    const int sr = tid >> 3;     // staged row within 64-row line
    const int sc = tid & 7;      // 16B slot within 128B row
    const int srcswz = (sc ^ (sr & 7)) * 16;   // involution w/ read-side XOR

    // one staging "line" = 64 rows x 64 cols bf16 = 8KB = one gl2lds16/thread
    auto stA = [&](int buf, int t, int ln) {
        int gr = bm * 256 + ln * 64 + sr;
        size_t e;
        if constexpr (MODE == 2)
            e = (size_t)(gr >> 11) * 2097152 + (size_t)t * 131072
                + (size_t)(gr & (TT - 1)) * 64;
        else
            e = (size_t)gr * (size_t)Kd + (size_t)t * 64;
        gl2lds16((const char*)(A + e) + srcswz,
                 (char*)&As[buf][0] + ln * 8192 + tid * 16);
    };
    auto stB = [&](int buf, int t, int ln) {
        int gr = bn * 256 + ln * 64 + sr;
        size_t e = (size_t)gr * (size_t)Kd + (size_t)t * 64;
        gl2lds16((const char*)(Bt + e) + srcswz,
                 (char*)&Bs[buf][0] + ln * 8192 + tid * 16);
    };

    f32x4 acc[8][4];
    #pragma unroll
    for (int m = 0; m < 8; ++m)
        #pragma unroll
        for (int n = 0; n < 4; ++n)
            acc[m][n] = f32x4{0.f, 0.f, 0.f, 0.f};

    // prologue: tile 0 (A+B, 8 loads) + tile 1's B (4 loads); wait tile 0
    stA(0, 0, 0); stA(0, 0, 1); stA(0, 0, 2); stA(0, 0, 3);
    stB(0, 0, 0); stB(0, 0, 1); stB(0, 0, 2); stB(0, 0, 3);
    stB(1, 1, 0); stB(1, 1, 1); stB(1, 1, 2); stB(1, 1, 3);
    waitvm<4>();
    BARF();

    const int swz = (lane15 & 7) << 4;   // read-side XOR (row&7 == lane15&7)
    bf16x8 aR[4][2];        // current m-half: [m-sub][kk]
    bf16x8 bR[4][2];        // all 4 n-frags:  [n][kk]

#define LDA_H(P, MH)                                                          \
    { _Pragma("unroll") for (int i = 0; i < 4; ++i)                           \
      _Pragma("unroll") for (int kk = 0; kk < 2; ++kk)                        \
        aR[i][kk] = *(const bf16x8*)((const char*)&As[P][0] +                 \
            (wm + MH * 64 + i * 16 + lane15) * 128 +                          \
            ((kk * 64 + quad * 16) ^ swz)); }

#define LDB_H(P, NHF)                                                         \
    { _Pragma("unroll") for (int j = 0; j < 2; ++j)                           \
      _Pragma("unroll") for (int kk = 0; kk < 2; ++kk)                        \
        bR[NHF * 2 + j][kk] = *(const bf16x8*)((const char*)&Bs[P][0] +       \
            (wn + (NHF * 2 + j) * 16 + lane15) * 128 +                        \
            ((kk * 64 + quad * 16) ^ swz)); }

#define MFMA_Q(MH, NHF)                                                       \
    { __builtin_amdgcn_s_setprio(1);                                          \
      _Pragma("unroll") for (int kk = 0; kk < 2; ++kk)                        \
      _Pragma("unroll") for (int i = 0; i < 4; ++i)                           \
      _Pragma("unroll") for (int j = 0; j < 2; ++j)                           \
        acc[MH * 4 + i][NHF * 2 + j] =                                        \
            __builtin_amdgcn_mfma_f32_16x16x32_bf16(                          \
                aR[i][kk], bR[NHF * 2 + j][kk], acc[MH * 4 + i][NHF * 2 + j], \
                0, 0, 0);                                                     \
      __builtin_amdgcn_s_setprio(0); }

    for (int t = 0; t < NK; ++t) {
        const int p = t & 1;
        const bool s1 = (t + 1 < NK), s2 = (t + 2 < NK);
        // ---- ph1: quadrant (m0, n0) + stage A(t+1) h0 -> buf p^1 ----
        LDA_H(p, 0);
        LDB_H(p, 0);
        if (s1) { stA(p ^ 1, t + 1, 0); stA(p ^ 1, t + 1, 1); }
        BARF(); LGK0();
        MFMA_Q(0, 0);
        BARF();
        // ---- ph2: quadrant (m0, n1) + stage A(t+1) h1 ----
        LDB_H(p, 1);
        if (s1) { stA(p ^ 1, t + 1, 2); stA(p ^ 1, t + 1, 3); }
        BARF(); LGK0();
        MFMA_Q(0, 1);
        BARF();
        // ---- ph3: quadrant (m1, n1) + stage B(t+2) h0 -> buf p ----
        LDA_H(p, 1);
        if (s2) { stB(p, t + 2, 0); stB(p, t + 2, 1); }
        BARF(); LGK0();
        MFMA_Q(1, 1);
        BARF();
        // ---- ph4: quadrant (m1, n0), no ds-reads; stage B(t+2) h1 ----
        if (s2) { stB(p, t + 2, 2); stB(p, t + 2, 3); }
        MFMA_Q(1, 0);
        if (s1) {
            if (s2) waitvm<4>();   // tile t+1 landed; B(t+2) in flight
            else    waitvm<0>();
            BARF();
        }
    }
#undef LDA_H
#undef LDB_H
#undef MFMA_Q

    if constexpr (MODE == 1) {
        const float SCQ = 0.125f * 1.4426950408889634f;   // folded into Q
        const int colbase = bn * 256 + wn;          // multiple of 64
        const int seg = colbase >> 10;              // 0=q 1=k 2=v (block-unif)
        const int h = (colbase & 1023) >> 6;        // head
        if (seg == 2) {
            // ---- fused V transpose: acc -> LDS [64 d][32 t] (pitch 40,
            // 80B rows) -> VbT[bh][d][t] coalesced. Per-wave scratch 5120B,
            // disjoint (waves 0-3 in As, 4-7 in Bs); seg is block-uniform.
            __syncthreads();   // all waves done reading As/Bs (K-loop)
            ushort_t* scr = ((w & 4) ? &Bs[0][0] : &As[0][0]) + (w & 3) * 2560;
            const int t0 = bm * 256 + wm;            // wave's first row (global)
            const int bq = t0 >> 11;                 // batch (const per wave)
            const int tb = t0 & (TT - 1);            // batch-LOCAL first t
            const size_t obase = (size_t)(bq * NH + h) * (TT * HD);
            #pragma unroll
            for (int hp = 0; hp < 4; ++hp) {         // 32 t per pass
                #pragma unroll
                for (int mp = 0; mp < 2; ++mp) {
                    int m = hp * 2 + mp;
                    #pragma unroll
                    for (int n = 0; n < 4; ++n) {
                        u16x4 v;
                        v[0] = f2bf(acc[m][n][0]);
                        v[1] = f2bf(acc[m][n][1]);
                        v[2] = f2bf(acc[m][n][2]);
                        v[3] = f2bf(acc[m][n][3]);
                        *(u16x4*)&scr[(n * 16 + lane15) * 40 +
                                      mp * 16 + quad * 4] = v;
                    }
                }
                LGK0();                               // own-wave writes visible
                __builtin_amdgcn_sched_barrier(0);
                #pragma unroll
                for (int i = 0; i < 4; ++i) {
                    int dd = i * 16 + (l >> 2);       // 16 d per iter
                    int tl = (l & 3) * 8;             // 8-t chunk
                    ushort8 vv = *(const ushort8*)&scr[dd * 40 + tl];
                    *(ushort8*)(VbT + obase + (size_t)dd * TT +
                                tb + hp * 32 + tl) = vv;
                }
                if (hp < 3) { LGK0(); __builtin_amdgcn_sched_barrier(0); }
            }
        } else {
            ushort_t* dst = (seg == 0) ? Qb : Kb;
            #pragma unroll
            for (int m = 0; m < 8; ++m) {
                int row0 = bm * 256 + wm + m * 16 + quad * 4;
                #pragma unroll
                for (int r = 0; r < 4; ++r) {
                    int row = row0 + r;
                    int b = row >> 11, t = row & (TT - 1);
                    size_t ob = ((size_t)(b * NH + h) * TT + t) * HD;
                    #pragma unroll
                    for (int n = 0; n < 2; ++n) {
                        int j = n * 16 + lane15;        // 0..31
                        float2 cs = rope[t * 32 + j];
                        float x1 = acc[m][n][r];        // d = j
                        float x2 = acc[m][n + 2][r];    // d = j+32
                        float y1 = x1 * cs.x - x2 * cs.y;
                        float y2 = x2 * cs.x + x1 * cs.y;
                        if (seg == 0) { y1 *= SCQ; y2 *= SCQ; }
                        dst[ob + j]      = f2bf(y1);
                        dst[ob + 32 + j] = f2bf(y2);
                    }
                }
            }
        }
    } else {
        #pragma unroll
        for (int m = 0; m < 8; ++m) {
            #pragma unroll
            for (int r = 0; r < 4; ++r) {
                size_t rb = (size_t)(bm * 256 + wm + m * 16 + quad * 4 + r) * N
                            + bn * 256 + wn;
                #pragma unroll
                for (int n = 0; n < 4; ++n)
                    CoutF[rb + n * 16 + lane15] = acc[m][n][r];
            }
        }
    }
}

// ---------------- flash attention (causal), O in place over Q --------------
// r10: 512 blocks (grid 8 x B*NH); each block runs q-tile PAIR {15-x, x}
// sequentially -> uniform 34 k-tiles/block, exactly 2 blocks/CU flat
// (optimal packing; fixes the 53%->35% residency decay of the 1024-block
// scheme where short blocks retired with no backfill).
// XCD-clustered remap (K/V L2 reuse). S^T = K*Q^T; P never touches LDS;
// defer-max on in-lane partial; l via ones-column MFMA; single barrier per
// k-tile via double-buffered K/V LDS; pitch-64 (128B row) XOR-swizzled
// tiles (zero-conflict, r9).
__global__ __launch_bounds__(512, 4) void attn_kernel(
    ushort_t* __restrict__ Qb, const ushort_t* __restrict__ Kb,
    const ushort_t* __restrict__ VbT) {
    __shared__ __attribute__((aligned(16))) ushort_t Ks[2][64 * 64]; // K [t][d]
    __shared__ __attribute__((aligned(16))) ushort_t Vs[2][64 * 64]; // V^T [d][t]

    const int tid = threadIdx.x;
    const int w = tid >> 6, l = tid & 63;
    const int lane15 = l & 15, quad = l >> 4;

    const int d = blockIdx.y * gridDim.x + blockIdx.x;   // 0..511
    const int xcd = d & 7, j = d >> 3;
    const int bh = xcd * 8 + (j & 7);
    const int xq = j >> 3;                               // 0..7
    const size_t base = (size_t)bh * (TT * HD);

    const int sr = tid >> 3;         // staging row 0..63
    const int sd = (tid & 7) * 8;    // staging col (elems), 16B per thread
    const int scol = (sd * 2) ^ ((sr & 7) << 4);   // swizzled write byte-col
    const ushort_t* kgb = Kb  + base + (size_t)sr * HD + sd;   // + kt*64*HD
    const ushort_t* vgb = VbT + base + (size_t)sr * TT + sd;   // + kt*64

    const int rsw = (lane15 & 7) << 4;   // read-side XOR
    const s16x4 ONES = {(short)0x3F80, (short)0x3F80,
                        (short)0x3F80, (short)0x3F80};   // bf16 1.0 x4

    #pragma unroll 1
    for (int seg = 0; seg < 2; ++seg) {
        const int qt = seg ? xq : 15 - xq;   // long tile first
        const int q0 = qt * 128;
        const int rbase = q0 + w * 16;       // wave owns 16 q-rows
        const int ktmax = 2 * qt + 1;        // >= 1 always

        // Q fragments (B-operand of S^T: n=lane15->qrow, k=quad*8+j->dim)
        bf16x8 qf0, qf1;
        {
            const ushort_t* qp = Qb + base + (size_t)(rbase + lane15) * HD
                                 + quad * 8;
            qf0 = *(const bf16x8*)qp;
            qf1 = *(const bf16x8*)(qp + 32);
        }

        f32x4 o[4];
        #pragma unroll
        for (int nt = 0; nt < 4; nt++) o[nt] = f32x4{0.f, 0.f, 0.f, 0.f};
        f32x4 lacc = f32x4{0.f, 0.f, 0.f, 0.f};   // row-sum, C-frag domain
        float mrow = -INFINITY;                    // per qrow=lane15

        if (seg) __syncthreads();   // prior segment's LDS readers done

        // prologue: tile 0 -> buf0; tile 1 -> regs
        ushort8 kr = *(const ushort8*)kgb;
        ushort8 vr = *(const ushort8*)vgb;
        *(ushort8*)((char*)&Ks[0][0] + sr * 128 + scol) = kr;
        *(ushort8*)((char*)&Vs[0][0] + sr * 128 + scol) = vr;
        kr = *(const ushort8*)(kgb + (size_t)64 * HD);
        vr = *(const ushort8*)(vgb + 64);
        __syncthreads();

        for (int kt = 0; kt <= ktmax; kt++) {
            const int buf = kt & 1;
            // at loop top kr/vr hold tile kt+1; write to the other buffer
            if (kt < ktmax) {
                *(ushort8*)((char*)&Ks[buf ^ 1][0] + sr * 128 + scol) = kr;
                *(ushort8*)((char*)&Vs[buf ^ 1][0] + sr * 128 + scol) = vr;
            }
            if (kt + 2 <= ktmax) {   // prefetch tile kt+2; overlaps compute
                kr = *(const ushort8*)(kgb + (size_t)(kt + 2) * 64 * HD);
                vr = *(const ushort8*)(vgb + (size_t)(kt + 2) * 64);
            }

            // waves 0-3's last tile can be fully causally masked: skip
            // compute (wave-uniform guard; barrier below stays outside)
            if (kt * 64 <= rbase + 15) {
                // S^T: D[kcol][qrow], kcol=c*16+quad*4+reg, qrow=lane15
                f32x4 s[4];
                #pragma unroll
                for (int c = 0; c < 4; c++) {
                    const char* krow = (const char*)&Ks[buf][0]
                                       + (c * 16 + lane15) * 128;
                    bf16x8 k0 = *(const bf16x8*)(krow + ((quad * 16) ^ rsw));
                    bf16x8 k1 = *(const bf16x8*)(krow + ((64 + quad * 16) ^ rsw));
                    f32x4 z = f32x4{0.f, 0.f, 0.f, 0.f};
                    z = __builtin_amdgcn_mfma_f32_16x16x32_bf16(k0, qf0, z, 0, 0, 0);
                    s[c] = __builtin_amdgcn_mfma_f32_16x16x32_bf16(k1, qf1, z, 0, 0, 0);
                }

                const int qrow = rbase + lane15;
                if (kt * 64 + 63 > rbase) {   // masking (wave-uniform)
                    #pragma unroll
                    for (int c = 0; c < 4; c++)
                        #pragma unroll
                        for (int r = 0; r < 4; r++)
                            if (kt * 64 + c * 16 + quad * 4 + r > qrow)
                                s[c][r] = -1e9f;
                }

                // in-lane partial max (v_max3 triples)
                float a0 = fmaxf(fmaxf(s[0][0], s[0][1]), s[0][2]);
                float a1 = fmaxf(fmaxf(s[0][3], s[1][0]), s[1][1]);
                float a2 = fmaxf(fmaxf(s[1][2], s[1][3]), s[2][0]);
                float a3 = fmaxf(fmaxf(s[2][1], s[2][2]), s[2][3]);
                float a4 = fmaxf(fmaxf(s[3][0], s[3][1]), s[3][2]);
                float mt = fmaxf(fmaxf(a0, a1), a2);
                mt = fmaxf(fmaxf(mt, a3), fmaxf(a4, s[3][3]));

                // defer-max: partial<=bound all lanes <=> row max <= bound
                if (!__all(mt - mrow <= 8.0f)) {
                    float mf = fmaxf(mt, __shfl_xor(mt, 16, 64));
                    mf = fmaxf(mf, __shfl_xor(mf, 32, 64));
                    float mn = fmaxf(mrow, mf);
                    float alpha = __builtin_amdgcn_exp2f(mrow - mn);
                    mrow = mn;
                    #pragma unroll
                    for (int r = 0; r < 4; r++) {
                        float aO = __shfl(alpha, quad * 4 + r, 64);
                        #pragma unroll
                        for (int nt = 0; nt < 4; nt++) o[nt][r] *= aO;
                        lacc[r] *= aO;
                    }
                }

                // P A-frags == S^T C-frag; l via ones-column MFMA
                #pragma unroll
                for (int c = 0; c < 4; c++) {
                    s16x4 pf;
                    #pragma unroll
                    for (int r = 0; r < 4; r++)
                        pf[r] = (short)f2bf(__builtin_amdgcn_exp2f(s[c][r] - mrow));
                    lacc = __builtin_amdgcn_mfma_f32_16x16x16bf16_1k(
                        pf, ONES, lacc, 0, 0, 0);
                    #pragma unroll
                    for (int nt = 0; nt < 4; nt++) {
                        s16x4 vf = *(const s16x4*)((const char*)&Vs[buf][0] +
                            (nt * 16 + lane15) * 128 +
                            ((c * 32 + quad * 8) ^ rsw));
                        o[nt] = __builtin_amdgcn_mfma_f32_16x16x16bf16_1k(
                            pf, vf, o[nt], 0, 0, 0);
                    }
                }
            }

            if (kt < ktmax) __syncthreads();   // release buffers
        }

        // epilogue: O in place over this wave's Q rows (head-major); l is
        // in the same C-frag domain as o -> no broadcast needed
        #pragma unroll
        for (int r = 0; r < 4; r++) {
            float lO = 1.0f / lacc[r];
            size_t rb = base + (size_t)(rbase + quad * 4 + r) * HD;
            #pragma unroll
            for (int nt = 0; nt < 4; nt++)
                Qb[rb + nt * 16 + lane15] = f2bf(o[nt][r] * lO);
        }
    }
}

// ---------------- launch ----------------
extern "C" void kernel_launch(void* const* d_in, const int* in_sizes, int n_in,
                              void* d_out, int out_size, void* d_ws, size_t ws_size,
                              hipStream_t stream) {
    const float* x    = (const float*)d_in[0];   // [8192][1024] fp32
    const float* wqkv = (const float*)d_in[1];   // [1024][3072] fp32
    const float* wout = (const float*)d_in[2];   // [1024][1024] fp32
    float* out = (float*)d_out;                  // [8192][1024] fp32

    // ws layout (72.5 MiB total):
    char* ws = (char*)d_ws;
    ushort_t* WqkvT = (ushort_t*)(ws);                        // [3072][1024] bf16
    ushort_t* WoutT = (ushort_t*)(ws + 6291456);              // [1024][1024] bf16
    float2*   rope  = (float2*)  (ws + 8388608);              // [2048*32]
    ushort_t* Xb    = (ushort_t*)(ws + 8912896);              // [8192][1024] bf16
    ushort_t* Qb    = (ushort_t*)(ws + 8912896 + 16777216);   // [64][2048][64]
    ushort_t* Kb    = (ushort_t*)(ws + 8912896 + 2 * 16777216);
    ushort_t* VbT   = (ushort_t*)(ws + 8912896 + 3 * 16777216); // [64][64][2048]
    // V is written directly transposed by GEMM1's epilogue (vtrans fused).

    prep<<<dim3(8448), 256, 0, stream>>>(x, Xb, wqkv, WqkvT, wout, WoutT, rope);

    // 256x256 tiles: grid1 = 12x32 = 384 blocks, grid2 = 4x32 = 128 blocks;
    // both %8==0 for XCD swizzle.
    gemm_bt<1><<<dim3(3 * CC / 256, MM / 256), 512, 0, stream>>>(
        Xb, WqkvT, nullptr, Qb, Kb, VbT, rope, MM, 3 * CC, CC);

    attn_kernel<<<dim3(8, BB * NH), 512, 0, stream>>>(Qb, Kb, VbT);

    gemm_bt<2><<<dim3(CC / 256, MM / 256), 512, 0, stream>>>(
        Qb, WoutT, out, nullptr, nullptr, nullptr, nullptr, MM, CC, CC);
}